// Round 3
// baseline (1040.276 us; speedup 1.0000x reference)
//
#include <hip/hip_runtime.h>
#include <hip/hip_bf16.h>

typedef __attribute__((ext_vector_type(8)))  short short8;
typedef __attribute__((ext_vector_type(16))) float floatx16;
typedef unsigned short ushort;

constexpr int SL  = 384;
constexpr int N2  = SL * SL;      // 147456
constexpr int CH  = 64;
constexpr int D1  = 788;
constexpr int D2  = 210;
constexpr int KG2 = 14;           // ceil(D2/16)
constexpr float EPSF = 1e-5f;

constexpr int TX = 32, TY = 8;
constexpr int NBLK = (SL / TX) * (SL / TY);   // 576

// ---- activation layout ("kc-blocked NHWC"):
//   record R = (y*4 + kc)*SL + x holds channels [kc*16, kc*16+16) as 16 bf16 (32B).

__device__ __forceinline__ float lrelu(float v){ return v >= 0.f ? v : 0.01f * v; }
__device__ __forceinline__ ushort f2b(float f){
  __hip_bfloat16 h = __float2bfloat16(f); return *(ushort*)&h;
}
__device__ __forceinline__ float b2f(ushort u){
  __hip_bfloat16 h = *(__hip_bfloat16*)&u; return __bfloat162float(h);
}

__device__ __forceinline__ float wred(float v){
  #pragma unroll
  for (int o = 32; o; o >>= 1) v += __shfl_down(v, o, 64);
  return v;
}

// ---------------- per-channel stats over fp32 NCHW (x1d only) ----------------
__global__ void stats_k(const float* __restrict__ x, int n, float* __restrict__ part){
  const int c = blockIdx.y, s = blockIdx.x, S = gridDim.x;
  const int chunk = (n + S - 1) / S;
  const int st = s * chunk, en = min(n, st + chunk);
  const float* p = x + (size_t)c * n;
  float sm = 0.f, ss = 0.f;
  for (int i = st + threadIdx.x; i < en; i += blockDim.x){
    float v = p[i]; sm += v; ss += v * v;
  }
  sm = wred(sm); ss = wred(ss);
  __shared__ float aux[8];
  const int wid = threadIdx.x >> 6, lane = threadIdx.x & 63;
  if (lane == 0){ aux[wid] = sm; aux[4 + wid] = ss; }
  __syncthreads();
  if (threadIdx.x == 0){
    part[((size_t)c * S + s) * 2]     = aux[0] + aux[1] + aux[2] + aux[3];
    part[((size_t)c * S + s) * 2 + 1] = aux[4] + aux[5] + aux[6] + aux[7];
  }
}

// parallel finalize: 16 threads per channel, width-16 shuffle reduce
__global__ void stats_final_k(const float* __restrict__ part, int C, int S, float ninv,
                              float* __restrict__ mean, float* __restrict__ rstd){
  const int c = blockIdx.x * 64 + (threadIdx.x >> 4);
  const int t = threadIdx.x & 15;
  if (c >= C) return;
  float sm = 0.f, ss = 0.f;
  for (int s = t; s < S; s += 16){
    sm += part[((size_t)c * S + s) * 2];
    ss += part[((size_t)c * S + s) * 2 + 1];
  }
  #pragma unroll
  for (int o = 8; o; o >>= 1){ sm += __shfl_down(sm, o, 16); ss += __shfl_down(ss, o, 16); }
  if (t == 0){
    const float m = sm * ninv;
    mean[c] = m;
    rstd[c] = rsqrtf(ss * ninv - m * m + EPSF);
  }
}

// parallel stats->affine: 16 threads per channel (C=64, one 1024-thread block)
__global__ void statsaffine_k(const float* __restrict__ part, int S, float ninv,
                              const float* __restrict__ g, const float* __restrict__ be,
                              int goff, float* __restrict__ ao, float* __restrict__ bo){
  const int c = threadIdx.x >> 4;
  const int t = threadIdx.x & 15;
  float sm = 0.f, ss = 0.f;
  for (int s = t; s < S; s += 16){
    sm += part[((size_t)c * S + s) * 2];
    ss += part[((size_t)c * S + s) * 2 + 1];
  }
  #pragma unroll
  for (int o = 8; o; o >>= 1){ sm += __shfl_down(sm, o, 16); ss += __shfl_down(ss, o, 16); }
  if (t == 0){
    const float m = sm * ninv;
    const float r = rsqrtf(ss * ninv - m * m + EPSF);
    const float a = r * g[goff + c];
    ao[c] = a;
    bo[c] = be[goff + c] - m * a;
  }
}

// ---------------- 1d branch (D1 split x4 for occupancy) ----------------
__global__ void rowcol_k(const float* __restrict__ x1d, const float* __restrict__ W1,
                         const float* __restrict__ r1, float* __restrict__ rcP){
  const int idx = blockIdx.x * 256 + threadIdx.x;   // (half, c, l)
  const int chunk = blockIdx.y;
  const int half = idx / (CH * SL);
  const int rem  = idx % (CH * SL);
  const int c = rem / SL, l = rem % SL;
  const int d0 = chunk * 197, d1 = min(D1, d0 + 197);
  const float* wp = W1 + (size_t)c * (2 * D1) + (size_t)half * D1;
  float acc = 0.f;
  for (int d = d0; d < d1; ++d)
    acc += wp[d] * (x1d[(size_t)d * SL + l] * r1[d]);
  rcP[(size_t)chunk * (2 * CH * SL) + idx] = acc;
}

__global__ void rowcol_stats_k(const float* __restrict__ rcP,
                               float* __restrict__ m1, float* __restrict__ rs1){
  const int c = blockIdx.x;
  float sr = 0, ssr = 0, sc = 0, ssc = 0;
  for (int i = threadIdx.x; i < SL; i += blockDim.x){
    float r = 0, q = 0;
    #pragma unroll
    for (int k = 0; k < 4; ++k){
      r += rcP[(size_t)k * (2*CH*SL) + c * SL + i];
      q += rcP[(size_t)k * (2*CH*SL) + CH*SL + c * SL + i];
    }
    sr += r; ssr += r * r; sc += q; ssc += q * q;
  }
  sr = wred(sr); ssr = wred(ssr); sc = wred(sc); ssc = wred(ssc);
  __shared__ float aux[16];
  const int wid = threadIdx.x >> 6, lane = threadIdx.x & 63;
  if (lane == 0){ aux[wid] = sr; aux[4+wid] = ssr; aux[8+wid] = sc; aux[12+wid] = ssc; }
  __syncthreads();
  if (threadIdx.x == 0){
    float a = 0, b = 0, d = 0, e = 0;
    for (int i = 0; i < 4; ++i){ a += aux[i]; b += aux[4+i]; d += aux[8+i]; e += aux[12+i]; }
    const float mr = a / SL, mc = d / SL;
    const float vr = b / SL - mr * mr, vc = e / SL - mc * mc;
    m1[c]  = mr + mc;
    rs1[c] = rsqrtf(vr + vc + EPSF);
  }
}

__global__ void rowcolT_k(const float* __restrict__ rcP,
                          const float* __restrict__ m1, const float* __restrict__ rs1,
                          const float* __restrict__ g1, const float* __restrict__ b1,
                          float* __restrict__ rowT, float* __restrict__ colT){
  const int i = blockIdx.x * 256 + threadIdx.x;   // 384*64
  const int l = i >> 6, c = i & 63;
  float r = 0, q = 0;
  #pragma unroll
  for (int k = 0; k < 4; ++k){
    r += rcP[(size_t)k * (2*CH*SL) + c * SL + l];
    q += rcP[(size_t)k * (2*CH*SL) + CH*SL + c * SL + l];
  }
  const float a  = rs1[c] * g1[c];
  const float bb = b1[c] - m1[c] * a;
  rowT[i] = r * a + bb;
  colT[i] = q * a;
}

// pair1: one thread = one 16-ch record of the kc-blocked layout
__global__ __launch_bounds__(256) void pair1n_k(const float* __restrict__ rowT,
                                                const float* __restrict__ colT,
                                                ushort* __restrict__ out){
  const size_t q = ((size_t)blockIdx.x * 256 + threadIdx.x) * 16;
  const int R = (int)(q >> 4);
  const int x = R % SL;
  const int t = R / SL;            // y*4 + kc
  const int kc = t & 3, y = t >> 2;
  const int c0 = kc * 16;
  const float4* rp = (const float4*)&rowT[y * 64 + c0];
  const float4* cp = (const float4*)&colT[x * 64 + c0];
  ushort o[16];
  #pragma unroll
  for (int k = 0; k < 4; ++k){
    float4 r = rp[k], cl = cp[k];
    o[4*k]   = f2b(lrelu(r.x + cl.x));
    o[4*k+1] = f2b(lrelu(r.y + cl.y));
    o[4*k+2] = f2b(lrelu(r.z + cl.z));
    o[4*k+3] = f2b(lrelu(r.w + cl.w));
  }
  *(short8*)&out[q]     = *(short8*)&o[0];
  *(short8*)&out[q + 8] = *(short8*)&o[8];
}

// ---------------- 2d branch: fused convert+stats (float4), then MFMA GEMM ----------
// x2 fp32 [d][p] -> bf16 flat-kc blocked: x2b[(g*N2 + p)*16 + (d-16g)], zero-pad d>=210.
__global__ __launch_bounds__(256) void x2cvt_k(const float* __restrict__ x2,
                                               ushort* __restrict__ x2b,
                                               float* __restrict__ part){
  const int g  = blockIdx.y;             // d-group 0..13
  const int p  = blockIdx.x * 1024 + threadIdx.x * 4;
  const int tid = threadIdx.x;
  float4 v[16];
  #pragma unroll
  for (int i = 0; i < 16; ++i){
    const int d = g * 16 + i;
    if (d < D2) v[i] = *(const float4*)&x2[(size_t)d * N2 + p];
    else        v[i] = make_float4(0.f, 0.f, 0.f, 0.f);
  }
  // write 4 consecutive records (128B contiguous)
  #pragma unroll
  for (int q = 0; q < 4; ++q){
    ushort o[16];
    #pragma unroll
    for (int i = 0; i < 16; ++i) o[i] = f2b(((const float*)&v[i])[q]);
    ushort* dp = &x2b[((size_t)g * N2 + p + q) * 16];
    *(short8*)&dp[0] = *(short8*)&o[0];
    *(short8*)&dp[8] = *(short8*)&o[8];
  }
  // per-d stats over this thread's 4 px
  float sm[16], ss[16];
  #pragma unroll
  for (int i = 0; i < 16; ++i){
    const float* vp = (const float*)&v[i];
    sm[i] = vp[0] + vp[1] + vp[2] + vp[3];
    ss[i] = vp[0]*vp[0] + vp[1]*vp[1] + vp[2]*vp[2] + vp[3]*vp[3];
  }
  __shared__ float aux[4][16][2];
  const int wid = tid >> 6, lane = tid & 63;
  #pragma unroll
  for (int i = 0; i < 16; ++i){
    float a = wred(sm[i]), b = wred(ss[i]);
    if (lane == 0){ aux[wid][i][0] = a; aux[wid][i][1] = b; }
  }
  __syncthreads();
  if (tid < 16){
    const int d = g * 16 + tid;
    if (d < D2){
      float a = aux[0][tid][0] + aux[1][tid][0] + aux[2][tid][0] + aux[3][tid][0];
      float b = aux[0][tid][1] + aux[1][tid][1] + aux[2][tid][1] + aux[3][tid][1];
      part[((size_t)d * gridDim.x + blockIdx.x) * 2]     = a;
      part[((size_t)d * gridDim.x + blockIdx.x) * 2 + 1] = b;
    }
  }
}

// W2 [oc][D2] fp32 * r2 -> bf16 A-fragment layout [kc(14)*2+half][oc(64)][j(8)]
__global__ void w2b_k(const float* __restrict__ W2, const float* __restrict__ r2,
                      ushort* __restrict__ w2b){
  const int i = blockIdx.x * 256 + threadIdx.x;   // 14336
  const int j    = i & 7;
  const int oc   = (i >> 3) & 63;
  const int half = (i >> 9) & 1;
  const int kc   = i >> 10;
  const int d    = kc * 16 + half * 8 + j;
  w2b[i] = (d < D2) ? f2b(W2[(size_t)oc * D2 + d] * r2[d]) : (ushort)0;
}

// MFMA GEMM: out[oc][px] = sum_d w2e[oc][d] * x2[d][px], K=224 (padded)
__global__ __launch_bounds__(256) void pair2m_k(const ushort* __restrict__ x2b,
                                                const ushort* __restrict__ w2b,
                                                ushort* __restrict__ out,
                                                float* __restrict__ part){
  __shared__ __align__(16) unsigned char ldsraw[256 * 144 + 4 * CH * 2 * 4];
  const int tid = threadIdx.x, lane = tid & 63, wid = tid >> 6;
  const int ln = lane & 31, half = lane >> 5;
  const int px0 = blockIdx.x * 256;
  floatx16 acc[2][2];
  #pragma unroll
  for (int mt = 0; mt < 2; ++mt)
    #pragma unroll
    for (int nt = 0; nt < 2; ++nt)
      #pragma unroll
      for (int r = 0; r < 16; ++r) acc[mt][nt][r] = 0.f;

  const int p0w = px0 + wid * 64 + ln;
  #pragma unroll
  for (int kc = 0; kc < KG2; ++kc){
    const ushort* ab = w2b + ((size_t)(kc * 2 + half)) * 512;
    short8 a0 = *(const short8*)&ab[ln * 8];
    short8 a1 = *(const short8*)&ab[256 + ln * 8];
    short8 b0 = *(const short8*)&x2b[((size_t)kc * N2 + p0w) * 16 + half * 8];
    short8 b1 = *(const short8*)&x2b[((size_t)kc * N2 + p0w + 32) * 16 + half * 8];
    acc[0][0] = __builtin_amdgcn_mfma_f32_32x32x16_bf16(a0, b0, acc[0][0], 0, 0, 0);
    acc[1][0] = __builtin_amdgcn_mfma_f32_32x32x16_bf16(a1, b0, acc[1][0], 0, 0, 0);
    acc[0][1] = __builtin_amdgcn_mfma_f32_32x32x16_bf16(a0, b1, acc[0][1], 0, 0, 0);
    acc[1][1] = __builtin_amdgcn_mfma_f32_32x32x16_bf16(a1, b1, acc[1][1], 0, 0, 0);
  }

  // epilogue: transpose via LDS, kc-blocked coalesced stores + fused stats
  ushort* tb = (ushort*)ldsraw;
  float*  sc = (float*)(ldsraw + 256 * 144);
  #pragma unroll
  for (int mt = 0; mt < 2; ++mt)
    #pragma unroll
    for (int nt = 0; nt < 2; ++nt){
      const int pxl = (2*wid + nt) * 32 + ln;
      #pragma unroll
      for (int rq = 0; rq < 4; ++rq){
        const int oc0 = mt*32 + 8*rq + 4*half;
        #pragma unroll
        for (int k = 0; k < 2; ++k){
          const int r = rq*4 + k*2;
          unsigned pk = (unsigned)f2b(acc[mt][nt][r]) | ((unsigned)f2b(acc[mt][nt][r+1]) << 16);
          *(unsigned*)&tb[pxl * 72 + oc0 + k*2] = pk;
        }
      }
    }
  #pragma unroll
  for (int mt = 0; mt < 2; ++mt)
    #pragma unroll
    for (int rq = 0; rq < 4; ++rq)
      #pragma unroll
      for (int t = 0; t < 4; ++t){
        const int r = rq*4 + t;
        float v  = acc[mt][0][r] + acc[mt][1][r];
        float v2 = acc[mt][0][r]*acc[mt][0][r] + acc[mt][1][r]*acc[mt][1][r];
        #pragma unroll
        for (int o = 1; o < 32; o <<= 1){ v += __shfl_xor(v, o, 64); v2 += __shfl_xor(v2, o, 64); }
        if (ln == 0){
          const int oc = mt*32 + 8*rq + 4*half + t;
          sc[(wid*CH + oc)*2] = v; sc[(wid*CH + oc)*2 + 1] = v2;
        }
      }
  __syncthreads();
  {
    const int px = lane & 31, h2 = lane >> 5;
    #pragma unroll
    for (int nt = 0; nt < 2; ++nt){
      const int rr = 2*wid + nt;
      const int p = px0 + rr*32 + px;
      const int y = p / SL, x = p - y * SL;
      #pragma unroll
      for (int h = 0; h < 2; ++h){
        const int kc = h2*2 + h;
        const ushort* sp = &tb[(rr*32 + px) * 72 + kc*16];
        ushort* dp = &out[((size_t)((y*4 + kc) * SL) + x) * 16];
        *(short8*)&dp[0] = *(const short8*)&sp[0];
        *(short8*)&dp[8] = *(const short8*)&sp[8];
      }
    }
  }
  if (tid < CH){
    float sm = 0.f, ss = 0.f;
    #pragma unroll
    for (int w = 0; w < 4; ++w){ sm += sc[(w*CH + tid)*2]; ss += sc[(w*CH + tid)*2 + 1]; }
    part[((size_t)tid * NBLK + blockIdx.x) * 2]     = sm;
    part[((size_t)tid * NBLK + blockIdx.x) * 2 + 1] = ss;
  }
}

// affine+leaky in place over kc-blocked layout (one thread = one 16-ch record)
__global__ __launch_bounds__(256) void norm_nhwc_k(ushort* __restrict__ x,
                                                   const float* __restrict__ a,
                                                   const float* __restrict__ b){
  const size_t q = ((size_t)blockIdx.x * 256 + threadIdx.x) * 16;
  const int R = (int)(q >> 4);
  const int c0 = ((R / SL) & 3) * 16;
  short8 v0 = *(short8*)&x[q], v1 = *(short8*)&x[q + 8];
  ushort o[16];
  #pragma unroll
  for (int k = 0; k < 8; ++k){
    o[k]   = f2b(lrelu(b2f((ushort)v0[k]) * a[c0+k]   + b[c0+k]));
    o[k+8] = f2b(lrelu(b2f((ushort)v1[k]) * a[c0+8+k] + b[c0+8+k]));
  }
  *(short8*)&x[q]     = *(short8*)&o[0];
  *(short8*)&x[q + 8] = *(short8*)&o[8];
}

// W3 [c][2CH] fp32 -> bf16 A-operand layout [kc(8)][half(2)][oc(64)][j(8)]
__global__ void w3b_k(const float* __restrict__ W3, ushort* __restrict__ w3b){
  const int i = blockIdx.x * 256 + threadIdx.x;   // 8192
  const int j    = i & 7;
  const int oc   = (i >> 3) & 63;
  const int half = (i >> 9) & 1;
  const int kc   = i >> 10;
  const int e    = kc * 16 + half * 8 + j;
  w3b[i] = f2b(W3[oc * (2 * CH) + e]);
}

// ---------------- MFMA mix: K=128 (A || Bb), coalesced kc-blocked B loads ----------
__global__ __launch_bounds__(256) void mixm_k(const ushort* __restrict__ A,
                                              const ushort* __restrict__ Bv,
                                              const ushort* __restrict__ w3b,
                                              ushort* __restrict__ out,
                                              float* __restrict__ part){
  __shared__ __align__(16) unsigned char ldsraw[256 * 144 + 4 * CH * 2 * 4];
  const int tid = threadIdx.x, lane = tid & 63, wid = tid >> 6;
  const int ln = lane & 31, half = lane >> 5;
  const int px0 = blockIdx.x * 256;
  floatx16 acc[2][2];
  #pragma unroll
  for (int mt = 0; mt < 2; ++mt)
    #pragma unroll
    for (int nt = 0; nt < 2; ++nt)
      #pragma unroll
      for (int r = 0; r < 16; ++r) acc[mt][nt][r] = 0.f;

  const int p0w = px0 + wid * 64 + ln;
  const int p1w = p0w + 32;
  const int y0 = p0w / SL, x0 = p0w - y0 * SL;
  const int y1 = p1w / SL, x1 = p1w - y1 * SL;
  #pragma unroll
  for (int kc = 0; kc < 8; ++kc){
    const ushort* src = (kc < 4) ? A : Bv;
    const int kcm = kc & 3;
    const ushort* ab = w3b + ((size_t)(kc * 2 + half)) * 512;
    short8 a0 = *(const short8*)&ab[ln * 8];
    short8 a1 = *(const short8*)&ab[256 + ln * 8];
    const size_t r0 = ((size_t)((y0 * 4 + kcm) * SL) + x0) * 16 + half * 8;
    const size_t r1 = ((size_t)((y1 * 4 + kcm) * SL) + x1) * 16 + half * 8;
    short8 b0 = *(const short8*)&src[r0];
    short8 b1 = *(const short8*)&src[r1];
    acc[0][0] = __builtin_amdgcn_mfma_f32_32x32x16_bf16(a0, b0, acc[0][0], 0, 0, 0);
    acc[1][0] = __builtin_amdgcn_mfma_f32_32x32x16_bf16(a1, b0, acc[1][0], 0, 0, 0);
    acc[0][1] = __builtin_amdgcn_mfma_f32_32x32x16_bf16(a0, b1, acc[0][1], 0, 0, 0);
    acc[1][1] = __builtin_amdgcn_mfma_f32_32x32x16_bf16(a1, b1, acc[1][1], 0, 0, 0);
  }

  // epilogue: transpose via LDS, kc-blocked coalesced stores + fused stats
  ushort* tb = (ushort*)ldsraw;
  float*  sc = (float*)(ldsraw + 256 * 144);
  #pragma unroll
  for (int mt = 0; mt < 2; ++mt)
    #pragma unroll
    for (int nt = 0; nt < 2; ++nt){
      const int pxl = (2*wid + nt) * 32 + ln;
      #pragma unroll
      for (int rq = 0; rq < 4; ++rq){
        const int oc0 = mt*32 + 8*rq + 4*half;
        #pragma unroll
        for (int k = 0; k < 2; ++k){
          const int r = rq*4 + k*2;
          unsigned pk = (unsigned)f2b(acc[mt][nt][r]) | ((unsigned)f2b(acc[mt][nt][r+1]) << 16);
          *(unsigned*)&tb[pxl * 72 + oc0 + k*2] = pk;
        }
      }
    }
  #pragma unroll
  for (int mt = 0; mt < 2; ++mt)
    #pragma unroll
    for (int rq = 0; rq < 4; ++rq)
      #pragma unroll
      for (int t = 0; t < 4; ++t){
        const int r = rq*4 + t;
        float v  = acc[mt][0][r] + acc[mt][1][r];
        float v2 = acc[mt][0][r]*acc[mt][0][r] + acc[mt][1][r]*acc[mt][1][r];
        #pragma unroll
        for (int o = 1; o < 32; o <<= 1){ v += __shfl_xor(v, o, 64); v2 += __shfl_xor(v2, o, 64); }
        if (ln == 0){
          const int oc = mt*32 + 8*rq + 4*half + t;
          sc[(wid*CH + oc)*2] = v; sc[(wid*CH + oc)*2 + 1] = v2;
        }
      }
  __syncthreads();
  {
    const int px = lane & 31, h2 = lane >> 5;
    #pragma unroll
    for (int nt = 0; nt < 2; ++nt){
      const int rr = 2*wid + nt;
      const int p = px0 + rr*32 + px;
      const int y = p / SL, x = p - y * SL;
      #pragma unroll
      for (int h = 0; h < 2; ++h){
        const int kc = h2*2 + h;
        const ushort* sp = &tb[(rr*32 + px) * 72 + kc*16];
        ushort* dp = &out[((size_t)((y*4 + kc) * SL) + x) * 16];
        *(short8*)&dp[0] = *(const short8*)&sp[0];
        *(short8*)&dp[8] = *(const short8*)&sp[8];
      }
    }
  }
  if (tid < CH){
    float sm = 0.f, ss = 0.f;
    #pragma unroll
    for (int w = 0; w < 4; ++w){ sm += sc[(w*CH + tid)*2]; ss += sc[(w*CH + tid)*2 + 1]; }
    part[((size_t)tid * NBLK + blockIdx.x) * 2]     = sm;
    part[((size_t)tid * NBLK + blockIdx.x) * 2 + 1] = ss;
  }
}

// ---------------- norm + residual; X fp32 NCHW (d_out), Xb bf16 kc-blocked ----------
__global__ __launch_bounds__(256) void norm_res_k(const ushort* __restrict__ src,
                                                  const float* __restrict__ a,
                                                  const float* __restrict__ b,
                                                  float* __restrict__ X,
                                                  ushort* __restrict__ Xb,
                                                  int doRes){
  __shared__ float tf[64 * 68];
  const int tid = threadIdx.x;
  const int p0 = blockIdx.x * 64;
  const int y0 = p0 / SL, x0 = p0 - y0 * SL;    // 64 | 384: block stays in one row
  const int pxl = tid >> 2, kc = tid & 3, c0 = kc * 16;
  {
    const ushort* sp = &src[((size_t)((y0*4 + kc) * SL) + x0 + pxl) * 16];
    short8 v0 = *(const short8*)&sp[0], v1 = *(const short8*)&sp[8];
    #pragma unroll
    for (int k = 0; k < 8; ++k){
      tf[(c0+k)*68 + pxl]   = lrelu(b2f((ushort)v0[k]) * a[c0+k]   + b[c0+k]);
      tf[(c0+8+k)*68 + pxl] = lrelu(b2f((ushort)v1[k]) * a[c0+8+k] + b[c0+8+k]);
    }
  }
  __syncthreads();
  {
    const int c = tid >> 2, part = tid & 3;
    const size_t gb = (size_t)c * N2 + p0 + part * 16;
    float w[16];
    #pragma unroll
    for (int k = 0; k < 16; ++k) w[k] = tf[c*68 + part*16 + k];
    if (doRes){
      #pragma unroll
      for (int k = 0; k < 16; ++k) w[k] += X[gb + k];
      #pragma unroll
      for (int k = 0; k < 16; ++k) tf[c*68 + part*16 + k] = w[k];
    }
    #pragma unroll
    for (int k = 0; k < 16; ++k) X[gb + k] = w[k];
  }
  if (Xb){
    __syncthreads();
    ushort o[16];
    #pragma unroll
    for (int k = 0; k < 16; ++k) o[k] = f2b(tf[(c0+k)*68 + pxl]);
    ushort* xp = &Xb[((size_t)((y0*4 + kc) * SL) + x0 + pxl) * 16];
    *(short8*)&xp[0] = *(short8*)&o[0];
    *(short8*)&xp[8] = *(short8*)&o[8];
  }
}

// conv weights [conv][oc][ic][3][3] fp32 -> bf16 [conv][tap][kc][half][oc][8j]
__global__ void wt_k(const float* __restrict__ w, ushort* __restrict__ wt){
  const int i = blockIdx.x * 256 + threadIdx.x;   // 368640
  const int j    = i & 7;
  const int oc   = (i >> 3) & 63;
  const int half = (i >> 9) & 1;
  const int kc   = (i >> 10) & 3;
  const int tap  = (i / 4096) % 9;
  const int cv   = i / 36864;
  const int ic   = kc * 16 + half * 8 + j;
  wt[i] = f2b(w[((size_t)(cv * CH + oc) * CH + ic) * 9 + tap]);
}

// ---------------- LDS-staged MFMA conv over kc-blocked layout -------------------
// Input tile (with halo) staged once per block (optionally applying affine+lrelu),
// B-fragments then read from LDS with an XOR swizzle (8-phase-minimum b128 reads).
template<int DIL, bool FUSE>
__global__ __launch_bounds__(256, 3) void convd_k(const ushort* __restrict__ in,
                                                  const ushort* __restrict__ wg,
                                                  const float* __restrict__ na,
                                                  const float* __restrict__ nb,
                                                  ushort* __restrict__ out,
                                                  float* __restrict__ part){
  constexpr int TH = TY + 2 * DIL;
  constexpr int TW = TX + 2 * DIL;
  constexpr int PHASES = (DIL == 4) ? 2 : 1;
  constexpr int KCP = 4 / PHASES;
  constexpr int STAGE_B = KCP * TH * TW * 32;
  constexpr int EPI_B = 256 * 144 + 4 * CH * 2 * 4;
  constexpr int LDS_B = STAGE_B > EPI_B ? STAGE_B : EPI_B;
  __shared__ __align__(16) unsigned char ldsraw[LDS_B];

  const int tid = threadIdx.x, lane = tid & 63, wid = tid >> 6;
  const int ln = lane & 31, half = lane >> 5;
  const int bx = blockIdx.x % (SL / TX), by = blockIdx.x / (SL / TX);

  floatx16 acc[2][2];
  #pragma unroll
  for (int mt = 0; mt < 2; ++mt)
    #pragma unroll
    for (int nt = 0; nt < 2; ++nt)
      #pragma unroll
      for (int r = 0; r < 16; ++r) acc[mt][nt][r] = 0.f;

  #pragma unroll
  for (int ph = 0; ph < PHASES; ++ph){
    if (ph) __syncthreads();             // all waves done reading previous phase
    // ---- stage tile (halo, zeros OOB), coalesced 16B pieces
    constexpr int PIECES = KCP * TH * TW * 2;
    for (int t = tid; t < PIECES; t += 256){
      const int half_ = t & 1;
      const int idx   = t >> 1;                 // (kcl*TH + ry)*TW + rx
      const int rx    = idx % TW;
      const int rem   = idx / TW;
      const int ry    = rem % TH;
      const int kcl   = rem / TH;
      const int kc    = ph * KCP + kcl;
      const int gy    = by * TY - DIL + ry;
      const int gx    = bx * TX - DIL + rx;
      const unsigned byteoff = ((unsigned)t * 16) ^ (((rx >> 2) & 1) << 4);
      short8 v = {0,0,0,0,0,0,0,0};
      if ((unsigned)gy < (unsigned)SL && (unsigned)gx < (unsigned)SL){
        v = *(const short8*)&in[(((size_t)(gy * 4 + kc)) * SL + gx) * 16 + half_ * 8];
        if (FUSE){
          const int c0 = kc * 16 + half_ * 8;
          float4 a0 = *(const float4*)&na[c0], a1 = *(const float4*)&na[c0 + 4];
          float4 b0 = *(const float4*)&nb[c0], b1 = *(const float4*)&nb[c0 + 4];
          ushort o[8];
          o[0] = f2b(lrelu(b2f((ushort)v[0]) * a0.x + b0.x));
          o[1] = f2b(lrelu(b2f((ushort)v[1]) * a0.y + b0.y));
          o[2] = f2b(lrelu(b2f((ushort)v[2]) * a0.z + b0.z));
          o[3] = f2b(lrelu(b2f((ushort)v[3]) * a0.w + b0.w));
          o[4] = f2b(lrelu(b2f((ushort)v[4]) * a1.x + b1.x));
          o[5] = f2b(lrelu(b2f((ushort)v[5]) * a1.y + b1.y));
          o[6] = f2b(lrelu(b2f((ushort)v[6]) * a1.z + b1.z));
          o[7] = f2b(lrelu(b2f((ushort)v[7]) * a1.w + b1.w));
          v = *(short8*)o;
        }
      }
      *(short8*)(ldsraw + byteoff) = v;
    }
    __syncthreads();
    // ---- compute from LDS
    #pragma unroll
    for (int tap = 0; tap < 9; ++tap){
      const int dy = (tap / 3 - 1) * DIL, dx = (tap % 3 - 1) * DIL;
      const int ry0 = 2 * wid + dy + DIL;
      const int rx  = ln + dx + DIL;
      const unsigned swz = ((unsigned)((rx >> 2) & 1)) << 4;
      #pragma unroll
      for (int kcl = 0; kcl < KCP; ++kcl){
        const int kc = ph * KCP + kcl;
        const ushort* ab = wg + ((size_t)((tap * 4 + kc) * 2 + half)) * 512;
        short8 a0 = *(const short8*)&ab[ln * 8];
        short8 a1 = *(const short8*)&ab[256 + ln * 8];
        const unsigned bo0 = ((unsigned)((((kcl * TH + ry0) * TW + rx) * 2 + half) * 16)) ^ swz;
        const unsigned bo1 = ((unsigned)((((kcl * TH + ry0 + 1) * TW + rx) * 2 + half) * 16)) ^ swz;
        short8 b0 = *(const short8*)(ldsraw + bo0);
        short8 b1 = *(const short8*)(ldsraw + bo1);
        acc[0][0] = __builtin_amdgcn_mfma_f32_32x32x16_bf16(a0, b0, acc[0][0], 0, 0, 0);
        acc[1][0] = __builtin_amdgcn_mfma_f32_32x32x16_bf16(a1, b0, acc[1][0], 0, 0, 0);
        acc[0][1] = __builtin_amdgcn_mfma_f32_32x32x16_bf16(a0, b1, acc[0][1], 0, 0, 0);
        acc[1][1] = __builtin_amdgcn_mfma_f32_32x32x16_bf16(a1, b1, acc[1][1], 0, 0, 0);
      }
    }
  }

  __syncthreads();   // before LDS reuse in epilogue
  // epilogue: LDS transpose -> kc-blocked coalesced stores + fused stats
  ushort* tb = (ushort*)ldsraw;
  float*  sc = (float*)(ldsraw + 256 * 144);
  #pragma unroll
  for (int mt = 0; mt < 2; ++mt)
    #pragma unroll
    for (int nt = 0; nt < 2; ++nt){
      const int pxl = (2*wid + nt) * 32 + ln;
      #pragma unroll
      for (int rq = 0; rq < 4; ++rq){
        const int oc0 = mt*32 + 8*rq + 4*half;
        #pragma unroll
        for (int k = 0; k < 2; ++k){
          const int r = rq*4 + k*2;
          unsigned pk = (unsigned)f2b(acc[mt][nt][r]) | ((unsigned)f2b(acc[mt][nt][r+1]) << 16);
          *(unsigned*)&tb[pxl * 72 + oc0 + k*2] = pk;
        }
      }
    }
  #pragma unroll
  for (int mt = 0; mt < 2; ++mt)
    #pragma unroll
    for (int rq = 0; rq < 4; ++rq)
      #pragma unroll
      for (int t = 0; t < 4; ++t){
        const int r = rq*4 + t;
        float v  = acc[mt][0][r] + acc[mt][1][r];
        float v2 = acc[mt][0][r]*acc[mt][0][r] + acc[mt][1][r]*acc[mt][1][r];
        #pragma unroll
        for (int o = 1; o < 32; o <<= 1){ v += __shfl_xor(v, o, 64); v2 += __shfl_xor(v2, o, 64); }
        if (ln == 0){
          const int oc = mt*32 + 8*rq + 4*half + t;
          sc[(wid*CH + oc)*2] = v; sc[(wid*CH + oc)*2 + 1] = v2;
        }
      }
  __syncthreads();
  {
    const int px = lane & 31, h2 = lane >> 5;
    #pragma unroll
    for (int nt = 0; nt < 2; ++nt){
      const int rr = 2*wid + nt;
      const int gy = by*TY + rr;
      #pragma unroll
      for (int h = 0; h < 2; ++h){
        const int kc = h2*2 + h;
        const ushort* sp = &tb[(rr*32 + px) * 72 + kc*16];
        ushort* dp = &out[((size_t)((gy*4 + kc) * SL) + bx*TX + px) * 16];
        *(short8*)&dp[0] = *(const short8*)&sp[0];
        *(short8*)&dp[8] = *(const short8*)&sp[8];
      }
    }
  }
  if (tid < CH){
    float sm = 0.f, ss = 0.f;
    #pragma unroll
    for (int w = 0; w < 4; ++w){ sm += sc[(w*CH + tid)*2]; ss += sc[(w*CH + tid)*2 + 1]; }
    part[((size_t)tid * NBLK + blockIdx.x) * 2]     = sm;
    part[((size_t)tid * NBLK + blockIdx.x) * 2 + 1] = ss;
  }
}

static void launch_conv(int dil, bool fuse, const ushort* src, const ushort* wgl,
                        const float* na, const float* nb,
                        ushort* dst, float* part, hipStream_t s){
  if (fuse){
    switch (dil){
      case 1:  convd_k<1,true><<<NBLK, 256, 0, s>>>(src, wgl, na, nb, dst, part); break;
      case 2:  convd_k<2,true><<<NBLK, 256, 0, s>>>(src, wgl, na, nb, dst, part); break;
      default: convd_k<4,true><<<NBLK, 256, 0, s>>>(src, wgl, na, nb, dst, part); break;
    }
  } else {
    switch (dil){
      case 1:  convd_k<1,false><<<NBLK, 256, 0, s>>>(src, wgl, na, nb, dst, part); break;
      case 2:  convd_k<2,false><<<NBLK, 256, 0, s>>>(src, wgl, na, nb, dst, part); break;
      default: convd_k<4,false><<<NBLK, 256, 0, s>>>(src, wgl, na, nb, dst, part); break;
    }
  }
}

extern "C" void kernel_launch(void* const* d_in, const int* in_sizes, int n_in,
                              void* d_out, int out_size, void* d_ws, size_t ws_size,
                              hipStream_t stream){
  const float* x1d    = (const float*)d_in[0];
  const float* x2     = (const float*)d_in[1];
  const float* W1     = (const float*)d_in[2];
  const float* g1     = (const float*)d_in[3];
  const float* b1     = (const float*)d_in[4];
  const float* W2     = (const float*)d_in[5];
  const float* res_w  = (const float*)d_in[11];
  const float* res_g  = (const float*)d_in[13];
  const float* res_be = (const float*)d_in[14];
  float* X = (float*)d_out;                        // fp32 NCHW residual stream

  unsigned char* wp = (unsigned char*)d_ws;
  ushort* A   = (ushort*)wp; wp += (size_t)N2 * 64 * 2;
  ushort* Bb  = (ushort*)wp; wp += (size_t)N2 * 64 * 2;
  ushort* Xb  = (ushort*)wp; wp += (size_t)N2 * 64 * 2;
  ushort* x2b = (ushort*)wp; wp += (size_t)KG2 * N2 * 16 * 2;
  ushort* wt  = (ushort*)wp; wp += (size_t)368640 * 2;
  ushort* w3b = (ushort*)wp; wp += (size_t)8192 * 2;
  ushort* w2b = (ushort*)wp; wp += (size_t)14336 * 2;
  float* fw = (float*)wp;
  float* rcP  = fw; fw += 4 * 2 * CH * SL;
  float* rowT = fw; fw += SL * CH;
  float* colT = fw; fw += SL * CH;
  float* s1m  = fw; fw += D1;   float* s1r = fw; fw += D1;
  float* s2m  = fw; fw += 256;  float* s2r = fw; fw += 256;
  float* m1   = fw; fw += 64;   float* rs1 = fw; fw += 64;
  float* aA   = fw; fw += 64;   float* bA  = fw; fw += 64;
  float* aB   = fw; fw += 64;   float* bB  = fw; fw += 64;
  float* part = fw; fw += CH * NBLK * 2;

  // ---- 1d branch
  stats_k<<<dim3(1, D1), 256, 0, stream>>>(x1d, SL, part);
  stats_final_k<<<13, 1024, 0, stream>>>(part, D1, 1, 1.f / SL, s1m, s1r);
  rowcol_k<<<dim3(2 * CH * SL / 256, 4), 256, 0, stream>>>(x1d, W1, s1r, rcP);
  rowcol_stats_k<<<CH, 256, 0, stream>>>(rcP, m1, rs1);
  rowcolT_k<<<SL * CH / 256, 256, 0, stream>>>(rcP, m1, rs1, g1, b1, rowT, colT);
  pair1n_k<<<N2 * 64 / 4096, 256, 0, stream>>>(rowT, colT, A);

  // ---- 2d branch: fused convert+stats -> MFMA GEMM
  x2cvt_k<<<dim3(144, KG2), 256, 0, stream>>>(x2, x2b, part);
  stats_final_k<<<4, 1024, 0, stream>>>(part, D2, 144, 1.f / N2, s2m, s2r);
  w2b_k<<<56, 256, 0, stream>>>(W2, s2r, w2b);
  pair2m_k<<<NBLK, 256, 0, stream>>>(x2b, w2b, Bb, part);
  statsaffine_k<<<1, 1024, 0, stream>>>(part, NBLK, 1.f / N2,
      (const float*)d_in[6], (const float*)d_in[7], 0, aA, bA);
  norm_nhwc_k<<<N2 * 64 / 4096, 256, 0, stream>>>(Bb, aA, bA);

  // ---- mix (MFMA, in-place over A) + bootstrap X
  w3b_k<<<32, 256, 0, stream>>>((const float*)d_in[8], w3b);
  mixm_k<<<NBLK, 256, 0, stream>>>(A, Bb, w3b, A, part);
  statsaffine_k<<<1, 1024, 0, stream>>>(part, NBLK, 1.f / N2,
      (const float*)d_in[9], (const float*)d_in[10], 0, aA, bA);
  norm_res_k<<<N2 / 64, 256, 0, stream>>>(A, aA, bA, X, Xb, 0);

  // ---- conv weights
  wt_k<<<368640 / 256, 256, 0, stream>>>(res_w, wt);

  // ---- 5 residual layers x 2 convs (norm between convs fused into conv2 staging)
  const int dil[5] = {1, 2, 4, 2, 1};
  for (int layer = 0; layer < 5; ++layer){
    const int d = dil[layer];
    const int li0 = layer * 2, li1 = li0 + 1;
    launch_conv(d, false, Xb, wt + (size_t)li0 * 36864, nullptr, nullptr, A, part, stream);
    statsaffine_k<<<1, 1024, 0, stream>>>(part, NBLK, 1.f / N2, res_g, res_be, li0 * CH, aA, bA);
    launch_conv(d, true, A, wt + (size_t)li1 * 36864, aA, bA, Bb, part, stream);
    statsaffine_k<<<1, 1024, 0, stream>>>(part, NBLK, 1.f / N2, res_g, res_be, li1 * CH, aB, bB);
    norm_res_k<<<N2 / 64, 256, 0, stream>>>(Bb, aB, bB, X,
        (layer == 4) ? nullptr : Xb, 1);
  }
}

// Round 5
// 1007.414 us; speedup vs baseline: 1.0326x; 1.0326x over previous
//
#include <hip/hip_runtime.h>
#include <hip/hip_bf16.h>

typedef __attribute__((ext_vector_type(8)))  short short8;
typedef __attribute__((ext_vector_type(16))) float floatx16;
typedef unsigned short ushort;

constexpr int SL  = 384;
constexpr int N2  = SL * SL;      // 147456
constexpr int CH  = 64;
constexpr int D1  = 788;
constexpr int D2  = 210;
constexpr int KG2 = 14;           // ceil(D2/16)
constexpr float EPSF = 1e-5f;

constexpr int TX = 32, TY = 8;
constexpr int NBLK = (SL / TX) * (SL / TY);   // 576

// ---- activation layout ("kc-blocked NHWC"):
//   record R = (y*4 + kc)*SL + x holds channels [kc*16, kc*16+16) as 16 bf16 (32B).

__device__ __forceinline__ float lrelu(float v){ return v >= 0.f ? v : 0.01f * v; }
__device__ __forceinline__ ushort f2b(float f){
  __hip_bfloat16 h = __float2bfloat16(f); return *(ushort*)&h;
}
__device__ __forceinline__ float b2f(ushort u){
  __hip_bfloat16 h = *(__hip_bfloat16*)&u; return __bfloat162float(h);
}

__device__ __forceinline__ float wred(float v){
  #pragma unroll
  for (int o = 32; o; o >>= 1) v += __shfl_down(v, o, 64);
  return v;
}

// ---------------- per-channel stats over fp32 NCHW (x1d only) ----------------
__global__ void stats_k(const float* __restrict__ x, int n, float* __restrict__ part){
  const int c = blockIdx.y, s = blockIdx.x, S = gridDim.x;
  const int chunk = (n + S - 1) / S;
  const int st = s * chunk, en = min(n, st + chunk);
  const float* p = x + (size_t)c * n;
  float sm = 0.f, ss = 0.f;
  for (int i = st + threadIdx.x; i < en; i += blockDim.x){
    float v = p[i]; sm += v; ss += v * v;
  }
  sm = wred(sm); ss = wred(ss);
  __shared__ float aux[8];
  const int wid = threadIdx.x >> 6, lane = threadIdx.x & 63;
  if (lane == 0){ aux[wid] = sm; aux[4 + wid] = ss; }
  __syncthreads();
  if (threadIdx.x == 0){
    part[((size_t)c * S + s) * 2]     = aux[0] + aux[1] + aux[2] + aux[3];
    part[((size_t)c * S + s) * 2 + 1] = aux[4] + aux[5] + aux[6] + aux[7];
  }
}

// parallel finalize: 16 threads per channel, width-16 shuffle reduce
__global__ void stats_final_k(const float* __restrict__ part, int C, int S, float ninv,
                              float* __restrict__ mean, float* __restrict__ rstd){
  const int c = blockIdx.x * 64 + (threadIdx.x >> 4);
  const int t = threadIdx.x & 15;
  if (c >= C) return;
  float sm = 0.f, ss = 0.f;
  for (int s = t; s < S; s += 16){
    sm += part[((size_t)c * S + s) * 2];
    ss += part[((size_t)c * S + s) * 2 + 1];
  }
  #pragma unroll
  for (int o = 8; o; o >>= 1){ sm += __shfl_down(sm, o, 16); ss += __shfl_down(ss, o, 16); }
  if (t == 0){
    const float m = sm * ninv;
    mean[c] = m;
    rstd[c] = rsqrtf(ss * ninv - m * m + EPSF);
  }
}

// parallel stats->affine: 16 threads per channel (C=64, one 1024-thread block)
__global__ void statsaffine_k(const float* __restrict__ part, int S, float ninv,
                              const float* __restrict__ g, const float* __restrict__ be,
                              int goff, float* __restrict__ ao, float* __restrict__ bo){
  const int c = threadIdx.x >> 4;
  const int t = threadIdx.x & 15;
  float sm = 0.f, ss = 0.f;
  for (int s = t; s < S; s += 16){
    sm += part[((size_t)c * S + s) * 2];
    ss += part[((size_t)c * S + s) * 2 + 1];
  }
  #pragma unroll
  for (int o = 8; o; o >>= 1){ sm += __shfl_down(sm, o, 16); ss += __shfl_down(ss, o, 16); }
  if (t == 0){
    const float m = sm * ninv;
    const float r = rsqrtf(ss * ninv - m * m + EPSF);
    const float a = r * g[goff + c];
    ao[c] = a;
    bo[c] = be[goff + c] - m * a;
  }
}

// ---------------- 1d branch (D1 split x4 for occupancy) ----------------
__global__ void rowcol_k(const float* __restrict__ x1d, const float* __restrict__ W1,
                         const float* __restrict__ r1, float* __restrict__ rcP){
  const int idx = blockIdx.x * 256 + threadIdx.x;   // (half, c, l)
  const int chunk = blockIdx.y;
  const int half = idx / (CH * SL);
  const int rem  = idx % (CH * SL);
  const int c = rem / SL, l = rem % SL;
  const int d0 = chunk * 197, d1 = min(D1, d0 + 197);
  const float* wp = W1 + (size_t)c * (2 * D1) + (size_t)half * D1;
  float acc = 0.f;
  for (int d = d0; d < d1; ++d)
    acc += wp[d] * (x1d[(size_t)d * SL + l] * r1[d]);
  rcP[(size_t)chunk * (2 * CH * SL) + idx] = acc;
}

__global__ void rowcol_stats_k(const float* __restrict__ rcP,
                               float* __restrict__ m1, float* __restrict__ rs1){
  const int c = blockIdx.x;
  float sr = 0, ssr = 0, sc = 0, ssc = 0;
  for (int i = threadIdx.x; i < SL; i += blockDim.x){
    float r = 0, q = 0;
    #pragma unroll
    for (int k = 0; k < 4; ++k){
      r += rcP[(size_t)k * (2*CH*SL) + c * SL + i];
      q += rcP[(size_t)k * (2*CH*SL) + CH*SL + c * SL + i];
    }
    sr += r; ssr += r * r; sc += q; ssc += q * q;
  }
  sr = wred(sr); ssr = wred(ssr); sc = wred(sc); ssc = wred(ssc);
  __shared__ float aux[16];
  const int wid = threadIdx.x >> 6, lane = threadIdx.x & 63;
  if (lane == 0){ aux[wid] = sr; aux[4+wid] = ssr; aux[8+wid] = sc; aux[12+wid] = ssc; }
  __syncthreads();
  if (threadIdx.x == 0){
    float a = 0, b = 0, d = 0, e = 0;
    for (int i = 0; i < 4; ++i){ a += aux[i]; b += aux[4+i]; d += aux[8+i]; e += aux[12+i]; }
    const float mr = a / SL, mc = d / SL;
    const float vr = b / SL - mr * mr, vc = e / SL - mc * mc;
    m1[c]  = mr + mc;
    rs1[c] = rsqrtf(vr + vc + EPSF);
  }
}

__global__ void rowcolT_k(const float* __restrict__ rcP,
                          const float* __restrict__ m1, const float* __restrict__ rs1,
                          const float* __restrict__ g1, const float* __restrict__ b1,
                          float* __restrict__ rowT, float* __restrict__ colT){
  const int i = blockIdx.x * 256 + threadIdx.x;   // 384*64
  const int l = i >> 6, c = i & 63;
  float r = 0, q = 0;
  #pragma unroll
  for (int k = 0; k < 4; ++k){
    r += rcP[(size_t)k * (2*CH*SL) + c * SL + l];
    q += rcP[(size_t)k * (2*CH*SL) + CH*SL + c * SL + l];
  }
  const float a  = rs1[c] * g1[c];
  const float bb = b1[c] - m1[c] * a;
  rowT[i] = r * a + bb;
  colT[i] = q * a;
}

// pair1: one thread = one 16-ch record of the kc-blocked layout
__global__ __launch_bounds__(256) void pair1n_k(const float* __restrict__ rowT,
                                                const float* __restrict__ colT,
                                                ushort* __restrict__ out){
  const size_t q = ((size_t)blockIdx.x * 256 + threadIdx.x) * 16;
  const int R = (int)(q >> 4);
  const int x = R % SL;
  const int t = R / SL;            // y*4 + kc
  const int kc = t & 3, y = t >> 2;
  const int c0 = kc * 16;
  const float4* rp = (const float4*)&rowT[y * 64 + c0];
  const float4* cp = (const float4*)&colT[x * 64 + c0];
  ushort o[16];
  #pragma unroll
  for (int k = 0; k < 4; ++k){
    float4 r = rp[k], cl = cp[k];
    o[4*k]   = f2b(lrelu(r.x + cl.x));
    o[4*k+1] = f2b(lrelu(r.y + cl.y));
    o[4*k+2] = f2b(lrelu(r.z + cl.z));
    o[4*k+3] = f2b(lrelu(r.w + cl.w));
  }
  *(short8*)&out[q]     = *(short8*)&o[0];
  *(short8*)&out[q + 8] = *(short8*)&o[8];
}

// ---------------- 2d branch: fused convert+stats, then MFMA GEMM ----------------
// x2 fp32 [d][p] -> bf16 flat-kc blocked: x2b[(g*N2 + p)*16 + (d-16g)], zero-pad d>=210.
// 1 px/thread: 16 scalar plane loads all in flight (16 VGPR), 32B contiguous write.
__global__ __launch_bounds__(256) void x2cvt_k(const float* __restrict__ x2,
                                               ushort* __restrict__ x2b,
                                               float* __restrict__ part){
  const int g  = blockIdx.y;             // d-group 0..13
  const int p  = blockIdx.x * 256 + threadIdx.x;
  const int tid = threadIdx.x;
  float v[16];
  #pragma unroll
  for (int i = 0; i < 16; ++i){
    const int d = g * 16 + i;
    v[i] = (d < D2) ? x2[(size_t)d * N2 + p] : 0.f;
  }
  ushort o[16];
  #pragma unroll
  for (int i = 0; i < 16; ++i) o[i] = f2b(v[i]);
  ushort* dp = &x2b[((size_t)g * N2 + p) * 16];
  *(short8*)&dp[0] = *(short8*)&o[0];
  *(short8*)&dp[8] = *(short8*)&o[8];
  // per-d stats
  __shared__ float aux[4][16][2];
  const int wid = tid >> 6, lane = tid & 63;
  #pragma unroll
  for (int i = 0; i < 16; ++i){
    float a = wred(v[i]), b = wred(v[i] * v[i]);
    if (lane == 0){ aux[wid][i][0] = a; aux[wid][i][1] = b; }
  }
  __syncthreads();
  if (tid < 16){
    const int d = g * 16 + tid;
    if (d < D2){
      float a = aux[0][tid][0] + aux[1][tid][0] + aux[2][tid][0] + aux[3][tid][0];
      float b = aux[0][tid][1] + aux[1][tid][1] + aux[2][tid][1] + aux[3][tid][1];
      part[((size_t)d * gridDim.x + blockIdx.x) * 2]     = a;
      part[((size_t)d * gridDim.x + blockIdx.x) * 2 + 1] = b;
    }
  }
}

// W2 [oc][D2] fp32 * r2 -> bf16 A-fragment layout [kc(14)*2+half][oc(64)][j(8)]
__global__ void w2b_k(const float* __restrict__ W2, const float* __restrict__ r2,
                      ushort* __restrict__ w2b){
  const int i = blockIdx.x * 256 + threadIdx.x;   // 14336
  const int j    = i & 7;
  const int oc   = (i >> 3) & 63;
  const int half = (i >> 9) & 1;
  const int kc   = i >> 10;
  const int d    = kc * 16 + half * 8 + j;
  w2b[i] = (d < D2) ? f2b(W2[(size_t)oc * D2 + d] * r2[d]) : (ushort)0;
}

// MFMA GEMM: out[oc][px] = sum_d w2e[oc][d] * x2[d][px], K=224 (padded)
__global__ __launch_bounds__(256) void pair2m_k(const ushort* __restrict__ x2b,
                                                const ushort* __restrict__ w2b,
                                                ushort* __restrict__ out,
                                                float* __restrict__ part){
  __shared__ __align__(16) unsigned char ldsraw[256 * 144 + 4 * CH * 2 * 4];
  const int tid = threadIdx.x, lane = tid & 63, wid = tid >> 6;
  const int ln = lane & 31, half = lane >> 5;
  const int px0 = blockIdx.x * 256;
  floatx16 acc[2][2];
  #pragma unroll
  for (int mt = 0; mt < 2; ++mt)
    #pragma unroll
    for (int nt = 0; nt < 2; ++nt)
      #pragma unroll
      for (int r = 0; r < 16; ++r) acc[mt][nt][r] = 0.f;

  const int p0w = px0 + wid * 64 + ln;
  #pragma unroll
  for (int kc = 0; kc < KG2; ++kc){
    const ushort* ab = w2b + ((size_t)(kc * 2 + half)) * 512;
    short8 a0 = *(const short8*)&ab[ln * 8];
    short8 a1 = *(const short8*)&ab[256 + ln * 8];
    short8 b0 = *(const short8*)&x2b[((size_t)kc * N2 + p0w) * 16 + half * 8];
    short8 b1 = *(const short8*)&x2b[((size_t)kc * N2 + p0w + 32) * 16 + half * 8];
    acc[0][0] = __builtin_amdgcn_mfma_f32_32x32x16_bf16(a0, b0, acc[0][0], 0, 0, 0);
    acc[1][0] = __builtin_amdgcn_mfma_f32_32x32x16_bf16(a1, b0, acc[1][0], 0, 0, 0);
    acc[0][1] = __builtin_amdgcn_mfma_f32_32x32x16_bf16(a0, b1, acc[0][1], 0, 0, 0);
    acc[1][1] = __builtin_amdgcn_mfma_f32_32x32x16_bf16(a1, b1, acc[1][1], 0, 0, 0);
  }

  // epilogue: transpose via LDS, kc-blocked coalesced stores + fused stats
  ushort* tb = (ushort*)ldsraw;
  float*  sc = (float*)(ldsraw + 256 * 144);
  #pragma unroll
  for (int mt = 0; mt < 2; ++mt)
    #pragma unroll
    for (int nt = 0; nt < 2; ++nt){
      const int pxl = (2*wid + nt) * 32 + ln;
      #pragma unroll
      for (int rq = 0; rq < 4; ++rq){
        const int oc0 = mt*32 + 8*rq + 4*half;
        #pragma unroll
        for (int k = 0; k < 2; ++k){
          const int r = rq*4 + k*2;
          unsigned pk = (unsigned)f2b(acc[mt][nt][r]) | ((unsigned)f2b(acc[mt][nt][r+1]) << 16);
          *(unsigned*)&tb[pxl * 72 + oc0 + k*2] = pk;
        }
      }
    }
  #pragma unroll
  for (int mt = 0; mt < 2; ++mt)
    #pragma unroll
    for (int rq = 0; rq < 4; ++rq)
      #pragma unroll
      for (int t = 0; t < 4; ++t){
        const int r = rq*4 + t;
        float v  = acc[mt][0][r] + acc[mt][1][r];
        float v2 = acc[mt][0][r]*acc[mt][0][r] + acc[mt][1][r]*acc[mt][1][r];
        #pragma unroll
        for (int o = 1; o < 32; o <<= 1){ v += __shfl_xor(v, o, 64); v2 += __shfl_xor(v2, o, 64); }
        if (ln == 0){
          const int oc = mt*32 + 8*rq + 4*half + t;
          sc[(wid*CH + oc)*2] = v; sc[(wid*CH + oc)*2 + 1] = v2;
        }
      }
  __syncthreads();
  {
    const int px = lane & 31, h2 = lane >> 5;
    #pragma unroll
    for (int nt = 0; nt < 2; ++nt){
      const int rr = 2*wid + nt;
      const int p = px0 + rr*32 + px;
      const int y = p / SL, x = p - y * SL;
      #pragma unroll
      for (int h = 0; h < 2; ++h){
        const int kc = h2*2 + h;
        const ushort* sp = &tb[(rr*32 + px) * 72 + kc*16];
        ushort* dp = &out[((size_t)((y*4 + kc) * SL) + x) * 16];
        *(short8*)&dp[0] = *(const short8*)&sp[0];
        *(short8*)&dp[8] = *(const short8*)&sp[8];
      }
    }
  }
  if (tid < CH){
    float sm = 0.f, ss = 0.f;
    #pragma unroll
    for (int w = 0; w < 4; ++w){ sm += sc[(w*CH + tid)*2]; ss += sc[(w*CH + tid)*2 + 1]; }
    part[((size_t)tid * NBLK + blockIdx.x) * 2]     = sm;
    part[((size_t)tid * NBLK + blockIdx.x) * 2 + 1] = ss;
  }
}

// affine+leaky in place over kc-blocked layout (one thread = one 16-ch record)
__global__ __launch_bounds__(256) void norm_nhwc_k(ushort* __restrict__ x,
                                                   const float* __restrict__ a,
                                                   const float* __restrict__ b){
  const size_t q = ((size_t)blockIdx.x * 256 + threadIdx.x) * 16;
  const int R = (int)(q >> 4);
  const int c0 = ((R / SL) & 3) * 16;
  short8 v0 = *(short8*)&x[q], v1 = *(short8*)&x[q + 8];
  ushort o[16];
  #pragma unroll
  for (int k = 0; k < 8; ++k){
    o[k]   = f2b(lrelu(b2f((ushort)v0[k]) * a[c0+k]   + b[c0+k]));
    o[k+8] = f2b(lrelu(b2f((ushort)v1[k]) * a[c0+8+k] + b[c0+8+k]));
  }
  *(short8*)&x[q]     = *(short8*)&o[0];
  *(short8*)&x[q + 8] = *(short8*)&o[8];
}

// W3 [c][2CH] fp32 -> bf16 A-operand layout [kc(8)][half(2)][oc(64)][j(8)]
__global__ void w3b_k(const float* __restrict__ W3, ushort* __restrict__ w3b){
  const int i = blockIdx.x * 256 + threadIdx.x;   // 8192
  const int j    = i & 7;
  const int oc   = (i >> 3) & 63;
  const int half = (i >> 9) & 1;
  const int kc   = i >> 10;
  const int e    = kc * 16 + half * 8 + j;
  w3b[i] = f2b(W3[oc * (2 * CH) + e]);
}

// ---------------- MFMA mix: K=128 (A || Bb), coalesced kc-blocked B loads ----------
__global__ __launch_bounds__(256) void mixm_k(const ushort* __restrict__ A,
                                              const ushort* __restrict__ Bv,
                                              const ushort* __restrict__ w3b,
                                              ushort* __restrict__ out,
                                              float* __restrict__ part){
  __shared__ __align__(16) unsigned char ldsraw[256 * 144 + 4 * CH * 2 * 4];
  const int tid = threadIdx.x, lane = tid & 63, wid = tid >> 6;
  const int ln = lane & 31, half = lane >> 5;
  const int px0 = blockIdx.x * 256;
  floatx16 acc[2][2];
  #pragma unroll
  for (int mt = 0; mt < 2; ++mt)
    #pragma unroll
    for (int nt = 0; nt < 2; ++nt)
      #pragma unroll
      for (int r = 0; r < 16; ++r) acc[mt][nt][r] = 0.f;

  const int p0w = px0 + wid * 64 + ln;
  const int p1w = p0w + 32;
  const int y0 = p0w / SL, x0 = p0w - y0 * SL;
  const int y1 = p1w / SL, x1 = p1w - y1 * SL;
  #pragma unroll
  for (int kc = 0; kc < 8; ++kc){
    const ushort* src = (kc < 4) ? A : Bv;
    const int kcm = kc & 3;
    const ushort* ab = w3b + ((size_t)(kc * 2 + half)) * 512;
    short8 a0 = *(const short8*)&ab[ln * 8];
    short8 a1 = *(const short8*)&ab[256 + ln * 8];
    const size_t r0 = ((size_t)((y0 * 4 + kcm) * SL) + x0) * 16 + half * 8;
    const size_t r1 = ((size_t)((y1 * 4 + kcm) * SL) + x1) * 16 + half * 8;
    short8 b0 = *(const short8*)&src[r0];
    short8 b1 = *(const short8*)&src[r1];
    acc[0][0] = __builtin_amdgcn_mfma_f32_32x32x16_bf16(a0, b0, acc[0][0], 0, 0, 0);
    acc[1][0] = __builtin_amdgcn_mfma_f32_32x32x16_bf16(a1, b0, acc[1][0], 0, 0, 0);
    acc[0][1] = __builtin_amdgcn_mfma_f32_32x32x16_bf16(a0, b1, acc[0][1], 0, 0, 0);
    acc[1][1] = __builtin_amdgcn_mfma_f32_32x32x16_bf16(a1, b1, acc[1][1], 0, 0, 0);
  }

  // epilogue: transpose via LDS, kc-blocked coalesced stores + fused stats
  ushort* tb = (ushort*)ldsraw;
  float*  sc = (float*)(ldsraw + 256 * 144);
  #pragma unroll
  for (int mt = 0; mt < 2; ++mt)
    #pragma unroll
    for (int nt = 0; nt < 2; ++nt){
      const int pxl = (2*wid + nt) * 32 + ln;
      #pragma unroll
      for (int rq = 0; rq < 4; ++rq){
        const int oc0 = mt*32 + 8*rq + 4*half;
        #pragma unroll
        for (int k = 0; k < 2; ++k){
          const int r = rq*4 + k*2;
          unsigned pk = (unsigned)f2b(acc[mt][nt][r]) | ((unsigned)f2b(acc[mt][nt][r+1]) << 16);
          *(unsigned*)&tb[pxl * 72 + oc0 + k*2] = pk;
        }
      }
    }
  #pragma unroll
  for (int mt = 0; mt < 2; ++mt)
    #pragma unroll
    for (int rq = 0; rq < 4; ++rq)
      #pragma unroll
      for (int t = 0; t < 4; ++t){
        const int r = rq*4 + t;
        float v  = acc[mt][0][r] + acc[mt][1][r];
        float v2 = acc[mt][0][r]*acc[mt][0][r] + acc[mt][1][r]*acc[mt][1][r];
        #pragma unroll
        for (int o = 1; o < 32; o <<= 1){ v += __shfl_xor(v, o, 64); v2 += __shfl_xor(v2, o, 64); }
        if (ln == 0){
          const int oc = mt*32 + 8*rq + 4*half + t;
          sc[(wid*CH + oc)*2] = v; sc[(wid*CH + oc)*2 + 1] = v2;
        }
      }
  __syncthreads();
  {
    const int px = lane & 31, h2 = lane >> 5;
    #pragma unroll
    for (int nt = 0; nt < 2; ++nt){
      const int rr = 2*wid + nt;
      const int p = px0 + rr*32 + px;
      const int y = p / SL, x = p - y * SL;
      #pragma unroll
      for (int h = 0; h < 2; ++h){
        const int kc = h2*2 + h;
        const ushort* sp = &tb[(rr*32 + px) * 72 + kc*16];
        ushort* dp = &out[((size_t)((y*4 + kc) * SL) + x) * 16];
        *(short8*)&dp[0] = *(const short8*)&sp[0];
        *(short8*)&dp[8] = *(const short8*)&sp[8];
      }
    }
  }
  if (tid < CH){
    float sm = 0.f, ss = 0.f;
    #pragma unroll
    for (int w = 0; w < 4; ++w){ sm += sc[(w*CH + tid)*2]; ss += sc[(w*CH + tid)*2 + 1]; }
    part[((size_t)tid * NBLK + blockIdx.x) * 2]     = sm;
    part[((size_t)tid * NBLK + blockIdx.x) * 2 + 1] = ss;
  }
}

// ---------------- norm + residual; X fp32 NCHW (d_out), Xb bf16 kc-blocked ----------
__global__ __launch_bounds__(256) void norm_res_k(const ushort* __restrict__ src,
                                                  const float* __restrict__ a,
                                                  const float* __restrict__ b,
                                                  float* __restrict__ X,
                                                  ushort* __restrict__ Xb,
                                                  int doRes){
  __shared__ float tf[64 * 68];
  const int tid = threadIdx.x;
  const int p0 = blockIdx.x * 64;
  const int y0 = p0 / SL, x0 = p0 - y0 * SL;    // 64 | 384: block stays in one row
  const int pxl = tid >> 2, kc = tid & 3, c0 = kc * 16;
  {
    const ushort* sp = &src[((size_t)((y0*4 + kc) * SL) + x0 + pxl) * 16];
    short8 v0 = *(const short8*)&sp[0], v1 = *(const short8*)&sp[8];
    #pragma unroll
    for (int k = 0; k < 8; ++k){
      tf[(c0+k)*68 + pxl]   = lrelu(b2f((ushort)v0[k]) * a[c0+k]   + b[c0+k]);
      tf[(c0+8+k)*68 + pxl] = lrelu(b2f((ushort)v1[k]) * a[c0+8+k] + b[c0+8+k]);
    }
  }
  __syncthreads();
  {
    const int c = tid >> 2, part = tid & 3;
    const size_t gb = (size_t)c * N2 + p0 + part * 16;
    float w[16];
    #pragma unroll
    for (int k = 0; k < 16; ++k) w[k] = tf[c*68 + part*16 + k];
    if (doRes){
      #pragma unroll
      for (int k = 0; k < 16; ++k) w[k] += X[gb + k];
      #pragma unroll
      for (int k = 0; k < 16; ++k) tf[c*68 + part*16 + k] = w[k];
    }
    #pragma unroll
    for (int k = 0; k < 16; ++k) X[gb + k] = w[k];
  }
  if (Xb){
    __syncthreads();
    ushort o[16];
    #pragma unroll
    for (int k = 0; k < 16; ++k) o[k] = f2b(tf[(c0+k)*68 + pxl]);
    ushort* xp = &Xb[((size_t)((y0*4 + kc) * SL) + x0 + pxl) * 16];
    *(short8*)&xp[0] = *(short8*)&o[0];
    *(short8*)&xp[8] = *(short8*)&o[8];
  }
}

// conv weights [conv][oc][ic][3][3] fp32 -> bf16 [conv][tap][kc][half][oc][8j]
__global__ void wt_k(const float* __restrict__ w, ushort* __restrict__ wt){
  const int i = blockIdx.x * 256 + threadIdx.x;   // 368640
  const int j    = i & 7;
  const int oc   = (i >> 3) & 63;
  const int half = (i >> 9) & 1;
  const int kc   = (i >> 10) & 3;
  const int tap  = (i / 4096) % 9;
  const int cv   = i / 36864;
  const int ic   = kc * 16 + half * 8 + j;
  wt[i] = f2b(w[((size_t)(cv * CH + oc) * CH + ic) * 9 + tap]);
}

// ---------------- LDS-staged MFMA conv over kc-blocked layout -------------------
template<int DIL, bool FUSE>
__global__ __launch_bounds__(256, 3) void convd_k(const ushort* __restrict__ in,
                                                  const ushort* __restrict__ wg,
                                                  const float* __restrict__ na,
                                                  const float* __restrict__ nb,
                                                  ushort* __restrict__ out,
                                                  float* __restrict__ part){
  constexpr int TH = TY + 2 * DIL;
  constexpr int TW = TX + 2 * DIL;
  constexpr int PHASES = (DIL >= 2) ? 2 : 1;
  constexpr int KCP = 4 / PHASES;
  constexpr int STAGE_B = KCP * TH * TW * 32;
  constexpr int EPI_B = 256 * 144 + 4 * CH * 2 * 4;
  constexpr int LDS_B = STAGE_B > EPI_B ? STAGE_B : EPI_B;
  __shared__ __align__(16) unsigned char ldsraw[LDS_B];

  const int tid = threadIdx.x, lane = tid & 63, wid = tid >> 6;
  const int ln = lane & 31, half = lane >> 5;
  const int bx = blockIdx.x % (SL / TX), by = blockIdx.x / (SL / TX);

  floatx16 acc[2][2];
  #pragma unroll
  for (int mt = 0; mt < 2; ++mt)
    #pragma unroll
    for (int nt = 0; nt < 2; ++nt)
      #pragma unroll
      for (int r = 0; r < 16; ++r) acc[mt][nt][r] = 0.f;

  #pragma unroll
  for (int ph = 0; ph < PHASES; ++ph){
    if (ph) __syncthreads();             // all waves done reading previous phase
    // ---- stage tile (halo, zeros OOB), coalesced 16B pieces
    constexpr int PIECES = KCP * TH * TW * 2;
    for (int t = tid; t < PIECES; t += 256){
      const int half_ = t & 1;
      const int idx   = t >> 1;                 // (kcl*TH + ry)*TW + rx
      const int rx    = idx % TW;
      const int rem   = idx / TW;
      const int ry    = rem % TH;
      const int kcl   = rem / TH;
      const int kc    = ph * KCP + kcl;
      const int gy    = by * TY - DIL + ry;
      const int gx    = bx * TX - DIL + rx;
      const unsigned byteoff = ((unsigned)t * 16) ^ (((rx >> 2) & 1) << 4);
      short8 v = {0,0,0,0,0,0,0,0};
      if ((unsigned)gy < (unsigned)SL && (unsigned)gx < (unsigned)SL){
        v = *(const short8*)&in[(((size_t)(gy * 4 + kc)) * SL + gx) * 16 + half_ * 8];
        if (FUSE){
          const int c0 = kc * 16 + half_ * 8;
          float4 a0 = *(const float4*)&na[c0], a1 = *(const float4*)&na[c0 + 4];
          float4 b0 = *(const float4*)&nb[c0], b1 = *(const float4*)&nb[c0 + 4];
          ushort o[8];
          o[0] = f2b(lrelu(b2f((ushort)v[0]) * a0.x + b0.x));
          o[1] = f2b(lrelu(b2f((ushort)v[1]) * a0.y + b0.y));
          o[2] = f2b(lrelu(b2f((ushort)v[2]) * a0.z + b0.z));
          o[3] = f2b(lrelu(b2f((ushort)v[3]) * a0.w + b0.w));
          o[4] = f2b(lrelu(b2f((ushort)v[4]) * a1.x + b1.x));
          o[5] = f2b(lrelu(b2f((ushort)v[5]) * a1.y + b1.y));
          o[6] = f2b(lrelu(b2f((ushort)v[6]) * a1.z + b1.z));
          o[7] = f2b(lrelu(b2f((ushort)v[7]) * a1.w + b1.w));
          v = *(short8*)o;
        }
      }
      *(short8*)(ldsraw + byteoff) = v;
    }
    __syncthreads();
    // ---- compute from LDS
    #pragma unroll
    for (int tap = 0; tap < 9; ++tap){
      const int dy = (tap / 3 - 1) * DIL, dx = (tap % 3 - 1) * DIL;
      const int ry0 = 2 * wid + dy + DIL;
      const int rx  = ln + dx + DIL;
      const unsigned swz = ((unsigned)((rx >> 2) & 1)) << 4;
      #pragma unroll
      for (int kcl = 0; kcl < KCP; ++kcl){
        const int kc = ph * KCP + kcl;
        const ushort* ab = wg + ((size_t)((tap * 4 + kc) * 2 + half)) * 512;
        short8 a0 = *(const short8*)&ab[ln * 8];
        short8 a1 = *(const short8*)&ab[256 + ln * 8];
        const unsigned bo0 = ((unsigned)((((kcl * TH + ry0) * TW + rx) * 2 + half) * 16)) ^ swz;
        const unsigned bo1 = ((unsigned)((((kcl * TH + ry0 + 1) * TW + rx) * 2 + half) * 16)) ^ swz;
        short8 b0 = *(const short8*)(ldsraw + bo0);
        short8 b1 = *(const short8*)(ldsraw + bo1);
        acc[0][0] = __builtin_amdgcn_mfma_f32_32x32x16_bf16(a0, b0, acc[0][0], 0, 0, 0);
        acc[1][0] = __builtin_amdgcn_mfma_f32_32x32x16_bf16(a1, b0, acc[1][0], 0, 0, 0);
        acc[0][1] = __builtin_amdgcn_mfma_f32_32x32x16_bf16(a0, b1, acc[0][1], 0, 0, 0);
        acc[1][1] = __builtin_amdgcn_mfma_f32_32x32x16_bf16(a1, b1, acc[1][1], 0, 0, 0);
      }
    }
  }

  __syncthreads();   // before LDS reuse in epilogue
  // epilogue: LDS transpose -> kc-blocked coalesced stores + fused stats
  ushort* tb = (ushort*)ldsraw;
  float*  sc = (float*)(ldsraw + 256 * 144);
  #pragma unroll
  for (int mt = 0; mt < 2; ++mt)
    #pragma unroll
    for (int nt = 0; nt < 2; ++nt){
      const int pxl = (2*wid + nt) * 32 + ln;
      #pragma unroll
      for (int rq = 0; rq < 4; ++rq){
        const int oc0 = mt*32 + 8*rq + 4*half;
        #pragma unroll
        for (int k = 0; k < 2; ++k){
          const int r = rq*4 + k*2;
          unsigned pk = (unsigned)f2b(acc[mt][nt][r]) | ((unsigned)f2b(acc[mt][nt][r+1]) << 16);
          *(unsigned*)&tb[pxl * 72 + oc0 + k*2] = pk;
        }
      }
    }
  #pragma unroll
  for (int mt = 0; mt < 2; ++mt)
    #pragma unroll
    for (int rq = 0; rq < 4; ++rq)
      #pragma unroll
      for (int t = 0; t < 4; ++t){
        const int r = rq*4 + t;
        float v  = acc[mt][0][r] + acc[mt][1][r];
        float v2 = acc[mt][0][r]*acc[mt][0][r] + acc[mt][1][r]*acc[mt][1][r];
        #pragma unroll
        for (int o = 1; o < 32; o <<= 1){ v += __shfl_xor(v, o, 64); v2 += __shfl_xor(v2, o, 64); }
        if (ln == 0){
          const int oc = mt*32 + 8*rq + 4*half + t;
          sc[(wid*CH + oc)*2] = v; sc[(wid*CH + oc)*2 + 1] = v2;
        }
      }
  __syncthreads();
  {
    const int px = lane & 31, h2 = lane >> 5;
    #pragma unroll
    for (int nt = 0; nt < 2; ++nt){
      const int rr = 2*wid + nt;
      const int gy = by*TY + rr;
      #pragma unroll
      for (int h = 0; h < 2; ++h){
        const int kc = h2*2 + h;
        const ushort* sp = &tb[(rr*32 + px) * 72 + kc*16];
        ushort* dp = &out[((size_t)((gy*4 + kc) * SL) + bx*TX + px) * 16];
        *(short8*)&dp[0] = *(const short8*)&sp[0];
        *(short8*)&dp[8] = *(const short8*)&sp[8];
      }
    }
  }
  if (tid < CH){
    float sm = 0.f, ss = 0.f;
    #pragma unroll
    for (int w = 0; w < 4; ++w){ sm += sc[(w*CH + tid)*2]; ss += sc[(w*CH + tid)*2 + 1]; }
    part[((size_t)tid * NBLK + blockIdx.x) * 2]     = sm;
    part[((size_t)tid * NBLK + blockIdx.x) * 2 + 1] = ss;
  }
}

static void launch_conv(int dil, bool fuse, const ushort* src, const ushort* wgl,
                        const float* na, const float* nb,
                        ushort* dst, float* part, hipStream_t s){
  if (fuse){
    switch (dil){
      case 1:  convd_k<1,true><<<NBLK, 256, 0, s>>>(src, wgl, na, nb, dst, part); break;
      case 2:  convd_k<2,true><<<NBLK, 256, 0, s>>>(src, wgl, na, nb, dst, part); break;
      default: convd_k<4,true><<<NBLK, 256, 0, s>>>(src, wgl, na, nb, dst, part); break;
    }
  } else {
    switch (dil){
      case 1:  convd_k<1,false><<<NBLK, 256, 0, s>>>(src, wgl, na, nb, dst, part); break;
      case 2:  convd_k<2,false><<<NBLK, 256, 0, s>>>(src, wgl, na, nb, dst, part); break;
      default: convd_k<4,false><<<NBLK, 256, 0, s>>>(src, wgl, na, nb, dst, part); break;
    }
  }
}

extern "C" void kernel_launch(void* const* d_in, const int* in_sizes, int n_in,
                              void* d_out, int out_size, void* d_ws, size_t ws_size,
                              hipStream_t stream){
  const float* x1d    = (const float*)d_in[0];
  const float* x2     = (const float*)d_in[1];
  const float* W1     = (const float*)d_in[2];
  const float* g1     = (const float*)d_in[3];
  const float* b1     = (const float*)d_in[4];
  const float* W2     = (const float*)d_in[5];
  const float* res_w  = (const float*)d_in[11];
  const float* res_g  = (const float*)d_in[13];
  const float* res_be = (const float*)d_in[14];
  float* X = (float*)d_out;                        // fp32 NCHW residual stream

  unsigned char* wp = (unsigned char*)d_ws;
  ushort* A   = (ushort*)wp; wp += (size_t)N2 * 64 * 2;
  ushort* Bb  = (ushort*)wp; wp += (size_t)N2 * 64 * 2;
  ushort* Xb  = (ushort*)wp; wp += (size_t)N2 * 64 * 2;
  ushort* x2b = (ushort*)wp; wp += (size_t)KG2 * N2 * 16 * 2;
  ushort* wt  = (ushort*)wp; wp += (size_t)368640 * 2;
  ushort* w3b = (ushort*)wp; wp += (size_t)8192 * 2;
  ushort* w2b = (ushort*)wp; wp += (size_t)14336 * 2;
  float* fw = (float*)wp;
  float* rcP  = fw; fw += 4 * 2 * CH * SL;
  float* rowT = fw; fw += SL * CH;
  float* colT = fw; fw += SL * CH;
  float* s1m  = fw; fw += D1;   float* s1r = fw; fw += D1;
  float* s2m  = fw; fw += 256;  float* s2r = fw; fw += 256;
  float* m1   = fw; fw += 64;   float* rs1 = fw; fw += 64;
  float* aA   = fw; fw += 64;   float* bA  = fw; fw += 64;
  float* aB   = fw; fw += 64;   float* bB  = fw; fw += 64;
  float* part = fw; fw += (size_t)D2 * NBLK * 2;   // big enough for d-stats (S=576)

  // ---- 1d branch
  stats_k<<<dim3(1, D1), 256, 0, stream>>>(x1d, SL, part);
  stats_final_k<<<13, 1024, 0, stream>>>(part, D1, 1, 1.f / SL, s1m, s1r);
  rowcol_k<<<dim3(2 * CH * SL / 256, 4), 256, 0, stream>>>(x1d, W1, s1r, rcP);
  rowcol_stats_k<<<CH, 256, 0, stream>>>(rcP, m1, rs1);
  rowcolT_k<<<SL * CH / 256, 256, 0, stream>>>(rcP, m1, rs1, g1, b1, rowT, colT);
  pair1n_k<<<N2 * 64 / 4096, 256, 0, stream>>>(rowT, colT, A);

  // ---- 2d branch: fused convert+stats -> MFMA GEMM
  x2cvt_k<<<dim3(N2 / 256, KG2), 256, 0, stream>>>(x2, x2b, part);
  stats_final_k<<<4, 1024, 0, stream>>>(part, D2, N2 / 256, 1.f / N2, s2m, s2r);
  w2b_k<<<56, 256, 0, stream>>>(W2, s2r, w2b);
  pair2m_k<<<NBLK, 256, 0, stream>>>(x2b, w2b, Bb, part);
  statsaffine_k<<<1, 1024, 0, stream>>>(part, NBLK, 1.f / N2,
      (const float*)d_in[6], (const float*)d_in[7], 0, aA, bA);
  norm_nhwc_k<<<N2 * 64 / 4096, 256, 0, stream>>>(Bb, aA, bA);

  // ---- mix (MFMA, in-place over A) + bootstrap X
  w3b_k<<<32, 256, 0, stream>>>((const float*)d_in[8], w3b);
  mixm_k<<<NBLK, 256, 0, stream>>>(A, Bb, w3b, A, part);
  statsaffine_k<<<1, 1024, 0, stream>>>(part, NBLK, 1.f / N2,
      (const float*)d_in[9], (const float*)d_in[10], 0, aA, bA);
  norm_res_k<<<N2 / 64, 256, 0, stream>>>(A, aA, bA, X, Xb, 0);

  // ---- conv weights
  wt_k<<<368640 / 256, 256, 0, stream>>>(res_w, wt);

  // ---- 5 residual layers x 2 convs (norm between convs fused into conv2 staging)
  const int dil[5] = {1, 2, 4, 2, 1};
  for (int layer = 0; layer < 5; ++layer){
    const int d = dil[layer];
    const int li0 = layer * 2, li1 = li0 + 1;
    launch_conv(d, false, Xb, wt + (size_t)li0 * 36864, nullptr, nullptr, A, part, stream);
    statsaffine_k<<<1, 1024, 0, stream>>>(part, NBLK, 1.f / N2, res_g, res_be, li0 * CH, aA, bA);
    launch_conv(d, true, A, wt + (size_t)li1 * 36864, aA, bA, Bb, part, stream);
    statsaffine_k<<<1, 1024, 0, stream>>>(part, NBLK, 1.f / N2, res_g, res_be, li1 * CH, aB, bB);
    norm_res_k<<<N2 / 64, 256, 0, stream>>>(Bb, aB, bB, X,
        (layer == 4) ? nullptr : Xb, 1);
  }
}

// Round 6
// 1006.397 us; speedup vs baseline: 1.0337x; 1.0010x over previous
//
#include <hip/hip_runtime.h>
#include <hip/hip_bf16.h>

typedef __attribute__((ext_vector_type(8)))  short short8;
typedef __attribute__((ext_vector_type(16))) float floatx16;
typedef unsigned short ushort;

constexpr int SL  = 384;
constexpr int N2  = SL * SL;      // 147456
constexpr int CH  = 64;
constexpr int D1  = 788;
constexpr int D2  = 210;
constexpr int KG2 = 14;           // ceil(D2/16)
constexpr float EPSF = 1e-5f;

constexpr int TX = 32, TY = 8;
constexpr int NBLK = (SL / TX) * (SL / TY);   // 576
constexpr int XCHUNK = 72;                     // x2cvt blocks in px dim

// ---- activation layout ("kc-blocked NHWC"):
//   record R = (y*4 + kc)*SL + x holds channels [kc*16, kc*16+16) as 16 bf16 (32B).

__device__ __forceinline__ float lrelu(float v){ return v >= 0.f ? v : 0.01f * v; }
__device__ __forceinline__ ushort f2b(float f){
  __hip_bfloat16 h = __float2bfloat16(f); return *(ushort*)&h;
}
__device__ __forceinline__ float b2f(ushort u){
  __hip_bfloat16 h = *(__hip_bfloat16*)&u; return __bfloat162float(h);
}

__device__ __forceinline__ float wred(float v){
  #pragma unroll
  for (int o = 32; o; o >>= 1) v += __shfl_down(v, o, 64);
  return v;
}

// ---------------- per-channel stats over fp32 NCHW (x1d only) ----------------
__global__ void stats_k(const float* __restrict__ x, int n, float* __restrict__ part){
  const int c = blockIdx.y, s = blockIdx.x, S = gridDim.x;
  const int chunk = (n + S - 1) / S;
  const int st = s * chunk, en = min(n, st + chunk);
  const float* p = x + (size_t)c * n;
  float sm = 0.f, ss = 0.f;
  for (int i = st + threadIdx.x; i < en; i += blockDim.x){
    float v = p[i]; sm += v; ss += v * v;
  }
  sm = wred(sm); ss = wred(ss);
  __shared__ float aux[8];
  const int wid = threadIdx.x >> 6, lane = threadIdx.x & 63;
  if (lane == 0){ aux[wid] = sm; aux[4 + wid] = ss; }
  __syncthreads();
  if (threadIdx.x == 0){
    part[((size_t)c * S + s) * 2]     = aux[0] + aux[1] + aux[2] + aux[3];
    part[((size_t)c * S + s) * 2 + 1] = aux[4] + aux[5] + aux[6] + aux[7];
  }
}

// parallel finalize: 16 threads per channel, width-16 shuffle reduce
__global__ void stats_final_k(const float* __restrict__ part, int C, int S, float ninv,
                              float* __restrict__ mean, float* __restrict__ rstd){
  const int c = blockIdx.x * 64 + (threadIdx.x >> 4);
  const int t = threadIdx.x & 15;
  if (c >= C) return;
  float sm = 0.f, ss = 0.f;
  for (int s = t; s < S; s += 16){
    sm += part[((size_t)c * S + s) * 2];
    ss += part[((size_t)c * S + s) * 2 + 1];
  }
  #pragma unroll
  for (int o = 8; o; o >>= 1){ sm += __shfl_down(sm, o, 16); ss += __shfl_down(ss, o, 16); }
  if (t == 0){
    const float m = sm * ninv;
    mean[c] = m;
    rstd[c] = rsqrtf(ss * ninv - m * m + EPSF);
  }
}

// parallel stats->affine: 16 threads per channel (C=64, one 1024-thread block)
__global__ void statsaffine_k(const float* __restrict__ part, int S, float ninv,
                              const float* __restrict__ g, const float* __restrict__ be,
                              int goff, float* __restrict__ ao, float* __restrict__ bo){
  const int c = threadIdx.x >> 4;
  const int t = threadIdx.x & 15;
  float sm = 0.f, ss = 0.f;
  for (int s = t; s < S; s += 16){
    sm += part[((size_t)c * S + s) * 2];
    ss += part[((size_t)c * S + s) * 2 + 1];
  }
  #pragma unroll
  for (int o = 8; o; o >>= 1){ sm += __shfl_down(sm, o, 16); ss += __shfl_down(ss, o, 16); }
  if (t == 0){
    const float m = sm * ninv;
    const float r = rsqrtf(ss * ninv - m * m + EPSF);
    const float a = r * g[goff + c];
    ao[c] = a;
    bo[c] = be[goff + c] - m * a;
  }
}

// ---------------- 1d branch (D1 split x4 for occupancy) ----------------
__global__ void rowcol_k(const float* __restrict__ x1d, const float* __restrict__ W1,
                         const float* __restrict__ r1, float* __restrict__ rcP){
  const int idx = blockIdx.x * 256 + threadIdx.x;   // (half, c, l)
  const int chunk = blockIdx.y;
  const int half = idx / (CH * SL);
  const int rem  = idx % (CH * SL);
  const int c = rem / SL, l = rem % SL;
  const int d0 = chunk * 197, d1 = min(D1, d0 + 197);
  const float* wp = W1 + (size_t)c * (2 * D1) + (size_t)half * D1;
  float acc = 0.f;
  for (int d = d0; d < d1; ++d)
    acc += wp[d] * (x1d[(size_t)d * SL + l] * r1[d]);
  rcP[(size_t)chunk * (2 * CH * SL) + idx] = acc;
}

__global__ void rowcol_stats_k(const float* __restrict__ rcP,
                               float* __restrict__ m1, float* __restrict__ rs1){
  const int c = blockIdx.x;
  float sr = 0, ssr = 0, sc = 0, ssc = 0;
  for (int i = threadIdx.x; i < SL; i += blockDim.x){
    float r = 0, q = 0;
    #pragma unroll
    for (int k = 0; k < 4; ++k){
      r += rcP[(size_t)k * (2*CH*SL) + c * SL + i];
      q += rcP[(size_t)k * (2*CH*SL) + CH*SL + c * SL + i];
    }
    sr += r; ssr += r * r; sc += q; ssc += q * q;
  }
  sr = wred(sr); ssr = wred(ssr); sc = wred(sc); ssc = wred(ssc);
  __shared__ float aux[16];
  const int wid = threadIdx.x >> 6, lane = threadIdx.x & 63;
  if (lane == 0){ aux[wid] = sr; aux[4+wid] = ssr; aux[8+wid] = sc; aux[12+wid] = ssc; }
  __syncthreads();
  if (threadIdx.x == 0){
    float a = 0, b = 0, d = 0, e = 0;
    for (int i = 0; i < 4; ++i){ a += aux[i]; b += aux[4+i]; d += aux[8+i]; e += aux[12+i]; }
    const float mr = a / SL, mc = d / SL;
    const float vr = b / SL - mr * mr, vc = e / SL - mc * mc;
    m1[c]  = mr + mc;
    rs1[c] = rsqrtf(vr + vc + EPSF);
  }
}

__global__ void rowcolT_k(const float* __restrict__ rcP,
                          const float* __restrict__ m1, const float* __restrict__ rs1,
                          const float* __restrict__ g1, const float* __restrict__ b1,
                          float* __restrict__ rowT, float* __restrict__ colT){
  const int i = blockIdx.x * 256 + threadIdx.x;   // 384*64
  const int l = i >> 6, c = i & 63;
  float r = 0, q = 0;
  #pragma unroll
  for (int k = 0; k < 4; ++k){
    r += rcP[(size_t)k * (2*CH*SL) + c * SL + l];
    q += rcP[(size_t)k * (2*CH*SL) + CH*SL + c * SL + l];
  }
  const float a  = rs1[c] * g1[c];
  const float bb = b1[c] - m1[c] * a;
  rowT[i] = r * a + bb;
  colT[i] = q * a;
}

// pair1: one thread = one 16-ch record of the kc-blocked layout
__global__ __launch_bounds__(256) void pair1n_k(const float* __restrict__ rowT,
                                                const float* __restrict__ colT,
                                                ushort* __restrict__ out){
  const size_t q = ((size_t)blockIdx.x * 256 + threadIdx.x) * 16;
  const int R = (int)(q >> 4);
  const int x = R % SL;
  const int t = R / SL;            // y*4 + kc
  const int kc = t & 3, y = t >> 2;
  const int c0 = kc * 16;
  const float4* rp = (const float4*)&rowT[y * 64 + c0];
  const float4* cp = (const float4*)&colT[x * 64 + c0];
  ushort o[16];
  #pragma unroll
  for (int k = 0; k < 4; ++k){
    float4 r = rp[k], cl = cp[k];
    o[4*k]   = f2b(lrelu(r.x + cl.x));
    o[4*k+1] = f2b(lrelu(r.y + cl.y));
    o[4*k+2] = f2b(lrelu(r.z + cl.z));
    o[4*k+3] = f2b(lrelu(r.w + cl.w));
  }
  *(short8*)&out[q]     = *(short8*)&o[0];
  *(short8*)&out[q + 8] = *(short8*)&o[8];
}

// ---------------- 2d branch: fused convert+stats, then MFMA GEMM ----------------
// x2 fp32 [d][p] -> bf16 flat-kc blocked; grid-stride (4 iters x float2) with a
// single amortized reduction tail per block. launch_bounds(256,2) -> up to 256 VGPR
// so all 16 plane loads stay in flight.
__global__ __launch_bounds__(256, 2) void x2cvt_k(const float* __restrict__ x2,
                                                  ushort* __restrict__ x2b,
                                                  float* __restrict__ part){
  const int g   = blockIdx.y;            // d-group 0..13
  const int tid = threadIdx.x;
  const int d0  = g * 16;
  float sm[16], ss[16];
  #pragma unroll
  for (int i = 0; i < 16; ++i){ sm[i] = 0.f; ss[i] = 0.f; }
  #pragma unroll
  for (int it = 0; it < 4; ++it){
    const int p = blockIdx.x * 2048 + it * 512 + tid * 2;
    float2 v[16];
    #pragma unroll
    for (int i = 0; i < 16; ++i){
      const int d = d0 + i;
      if (d < D2) v[i] = *(const float2*)&x2[(size_t)d * N2 + p];
      else        v[i] = make_float2(0.f, 0.f);
    }
    ushort o[32];
    #pragma unroll
    for (int i = 0; i < 16; ++i){
      o[i]      = f2b(v[i].x);
      o[16 + i] = f2b(v[i].y);
      sm[i] += v[i].x + v[i].y;
      ss[i] += v[i].x * v[i].x + v[i].y * v[i].y;
    }
    ushort* dp = &x2b[((size_t)g * N2 + p) * 16];
    *(short8*)&dp[0]  = *(short8*)&o[0];
    *(short8*)&dp[8]  = *(short8*)&o[8];
    *(short8*)&dp[16] = *(short8*)&o[16];
    *(short8*)&dp[24] = *(short8*)&o[24];
  }
  __shared__ float aux[4][16][2];
  const int wid = tid >> 6, lane = tid & 63;
  #pragma unroll
  for (int i = 0; i < 16; ++i){
    float a = wred(sm[i]), b = wred(ss[i]);
    if (lane == 0){ aux[wid][i][0] = a; aux[wid][i][1] = b; }
  }
  __syncthreads();
  if (tid < 16){
    const int d = d0 + tid;
    if (d < D2){
      float a = aux[0][tid][0] + aux[1][tid][0] + aux[2][tid][0] + aux[3][tid][0];
      float b = aux[0][tid][1] + aux[1][tid][1] + aux[2][tid][1] + aux[3][tid][1];
      part[((size_t)d * XCHUNK + blockIdx.x) * 2]     = a;
      part[((size_t)d * XCHUNK + blockIdx.x) * 2 + 1] = b;
    }
  }
}

// W2 [oc][D2] fp32 * r2 -> bf16 A-fragment layout [kc(14)*2+half][oc(64)][j(8)]
__global__ void w2b_k(const float* __restrict__ W2, const float* __restrict__ r2,
                      ushort* __restrict__ w2b){
  const int i = blockIdx.x * 256 + threadIdx.x;   // 14336
  const int j    = i & 7;
  const int oc   = (i >> 3) & 63;
  const int half = (i >> 9) & 1;
  const int kc   = i >> 10;
  const int d    = kc * 16 + half * 8 + j;
  w2b[i] = (d < D2) ? f2b(W2[(size_t)oc * D2 + d] * r2[d]) : (ushort)0;
}

// MFMA GEMM: out[oc][px] = sum_d w2e[oc][d] * x2[d][px], K=224 (padded)
__global__ __launch_bounds__(256) void pair2m_k(const ushort* __restrict__ x2b,
                                                const ushort* __restrict__ w2b,
                                                ushort* __restrict__ out,
                                                float* __restrict__ part){
  __shared__ __align__(16) unsigned char ldsraw[256 * 144 + 4 * CH * 2 * 4];
  const int tid = threadIdx.x, lane = tid & 63, wid = tid >> 6;
  const int ln = lane & 31, half = lane >> 5;
  const int px0 = blockIdx.x * 256;
  floatx16 acc[2][2];
  #pragma unroll
  for (int mt = 0; mt < 2; ++mt)
    #pragma unroll
    for (int nt = 0; nt < 2; ++nt)
      #pragma unroll
      for (int r = 0; r < 16; ++r) acc[mt][nt][r] = 0.f;

  const int p0w = px0 + wid * 64 + ln;
  #pragma unroll
  for (int kc = 0; kc < KG2; ++kc){
    const ushort* ab = w2b + ((size_t)(kc * 2 + half)) * 512;
    short8 a0 = *(const short8*)&ab[ln * 8];
    short8 a1 = *(const short8*)&ab[256 + ln * 8];
    short8 b0 = *(const short8*)&x2b[((size_t)kc * N2 + p0w) * 16 + half * 8];
    short8 b1 = *(const short8*)&x2b[((size_t)kc * N2 + p0w + 32) * 16 + half * 8];
    acc[0][0] = __builtin_amdgcn_mfma_f32_32x32x16_bf16(a0, b0, acc[0][0], 0, 0, 0);
    acc[1][0] = __builtin_amdgcn_mfma_f32_32x32x16_bf16(a1, b0, acc[1][0], 0, 0, 0);
    acc[0][1] = __builtin_amdgcn_mfma_f32_32x32x16_bf16(a0, b1, acc[0][1], 0, 0, 0);
    acc[1][1] = __builtin_amdgcn_mfma_f32_32x32x16_bf16(a1, b1, acc[1][1], 0, 0, 0);
  }

  // epilogue: transpose via LDS, kc-blocked coalesced stores + fused stats
  ushort* tb = (ushort*)ldsraw;
  float*  sc = (float*)(ldsraw + 256 * 144);
  #pragma unroll
  for (int mt = 0; mt < 2; ++mt)
    #pragma unroll
    for (int nt = 0; nt < 2; ++nt){
      const int pxl = (2*wid + nt) * 32 + ln;
      #pragma unroll
      for (int rq = 0; rq < 4; ++rq){
        const int oc0 = mt*32 + 8*rq + 4*half;
        #pragma unroll
        for (int k = 0; k < 2; ++k){
          const int r = rq*4 + k*2;
          unsigned pk = (unsigned)f2b(acc[mt][nt][r]) | ((unsigned)f2b(acc[mt][nt][r+1]) << 16);
          *(unsigned*)&tb[pxl * 72 + oc0 + k*2] = pk;
        }
      }
    }
  #pragma unroll
  for (int mt = 0; mt < 2; ++mt)
    #pragma unroll
    for (int rq = 0; rq < 4; ++rq)
      #pragma unroll
      for (int t = 0; t < 4; ++t){
        const int r = rq*4 + t;
        float v  = acc[mt][0][r] + acc[mt][1][r];
        float v2 = acc[mt][0][r]*acc[mt][0][r] + acc[mt][1][r]*acc[mt][1][r];
        #pragma unroll
        for (int o = 1; o < 32; o <<= 1){ v += __shfl_xor(v, o, 64); v2 += __shfl_xor(v2, o, 64); }
        if (ln == 0){
          const int oc = mt*32 + 8*rq + 4*half + t;
          sc[(wid*CH + oc)*2] = v; sc[(wid*CH + oc)*2 + 1] = v2;
        }
      }
  __syncthreads();
  {
    const int px = lane & 31, h2 = lane >> 5;
    #pragma unroll
    for (int nt = 0; nt < 2; ++nt){
      const int rr = 2*wid + nt;
      const int p = px0 + rr*32 + px;
      const int y = p / SL, x = p - y * SL;
      #pragma unroll
      for (int h = 0; h < 2; ++h){
        const int kc = h2*2 + h;
        const ushort* sp = &tb[(rr*32 + px) * 72 + kc*16];
        ushort* dp = &out[((size_t)((y*4 + kc) * SL) + x) * 16];
        *(short8*)&dp[0] = *(const short8*)&sp[0];
        *(short8*)&dp[8] = *(const short8*)&sp[8];
      }
    }
  }
  if (tid < CH){
    float sm = 0.f, ss = 0.f;
    #pragma unroll
    for (int w = 0; w < 4; ++w){ sm += sc[(w*CH + tid)*2]; ss += sc[(w*CH + tid)*2 + 1]; }
    part[((size_t)tid * NBLK + blockIdx.x) * 2]     = sm;
    part[((size_t)tid * NBLK + blockIdx.x) * 2 + 1] = ss;
  }
}

// affine+leaky in place over kc-blocked layout (one thread = one 16-ch record)
__global__ __launch_bounds__(256) void norm_nhwc_k(ushort* __restrict__ x,
                                                   const float* __restrict__ a,
                                                   const float* __restrict__ b){
  const size_t q = ((size_t)blockIdx.x * 256 + threadIdx.x) * 16;
  const int R = (int)(q >> 4);
  const int c0 = ((R / SL) & 3) * 16;
  short8 v0 = *(short8*)&x[q], v1 = *(short8*)&x[q + 8];
  ushort o[16];
  #pragma unroll
  for (int k = 0; k < 8; ++k){
    o[k]   = f2b(lrelu(b2f((ushort)v0[k]) * a[c0+k]   + b[c0+k]));
    o[k+8] = f2b(lrelu(b2f((ushort)v1[k]) * a[c0+8+k] + b[c0+8+k]));
  }
  *(short8*)&x[q]     = *(short8*)&o[0];
  *(short8*)&x[q + 8] = *(short8*)&o[8];
}

// W3 [c][2CH] fp32 -> bf16 A-operand layout [kc(8)][half(2)][oc(64)][j(8)]
__global__ void w3b_k(const float* __restrict__ W3, ushort* __restrict__ w3b){
  const int i = blockIdx.x * 256 + threadIdx.x;   // 8192
  const int j    = i & 7;
  const int oc   = (i >> 3) & 63;
  const int half = (i >> 9) & 1;
  const int kc   = i >> 10;
  const int e    = kc * 16 + half * 8 + j;
  w3b[i] = f2b(W3[oc * (2 * CH) + e]);
}

// ---------------- MFMA mix: K=128 (A || Bb), coalesced kc-blocked B loads ----------
__global__ __launch_bounds__(256) void mixm_k(const ushort* __restrict__ A,
                                              const ushort* __restrict__ Bv,
                                              const ushort* __restrict__ w3b,
                                              ushort* __restrict__ out,
                                              float* __restrict__ part){
  __shared__ __align__(16) unsigned char ldsraw[256 * 144 + 4 * CH * 2 * 4];
  const int tid = threadIdx.x, lane = tid & 63, wid = tid >> 6;
  const int ln = lane & 31, half = lane >> 5;
  const int px0 = blockIdx.x * 256;
  floatx16 acc[2][2];
  #pragma unroll
  for (int mt = 0; mt < 2; ++mt)
    #pragma unroll
    for (int nt = 0; nt < 2; ++nt)
      #pragma unroll
      for (int r = 0; r < 16; ++r) acc[mt][nt][r] = 0.f;

  const int p0w = px0 + wid * 64 + ln;
  const int p1w = p0w + 32;
  const int y0 = p0w / SL, x0 = p0w - y0 * SL;
  const int y1 = p1w / SL, x1 = p1w - y1 * SL;
  #pragma unroll
  for (int kc = 0; kc < 8; ++kc){
    const ushort* src = (kc < 4) ? A : Bv;
    const int kcm = kc & 3;
    const ushort* ab = w3b + ((size_t)(kc * 2 + half)) * 512;
    short8 a0 = *(const short8*)&ab[ln * 8];
    short8 a1 = *(const short8*)&ab[256 + ln * 8];
    const size_t r0 = ((size_t)((y0 * 4 + kcm) * SL) + x0) * 16 + half * 8;
    const size_t r1 = ((size_t)((y1 * 4 + kcm) * SL) + x1) * 16 + half * 8;
    short8 b0 = *(const short8*)&src[r0];
    short8 b1 = *(const short8*)&src[r1];
    acc[0][0] = __builtin_amdgcn_mfma_f32_32x32x16_bf16(a0, b0, acc[0][0], 0, 0, 0);
    acc[1][0] = __builtin_amdgcn_mfma_f32_32x32x16_bf16(a1, b0, acc[1][0], 0, 0, 0);
    acc[0][1] = __builtin_amdgcn_mfma_f32_32x32x16_bf16(a0, b1, acc[0][1], 0, 0, 0);
    acc[1][1] = __builtin_amdgcn_mfma_f32_32x32x16_bf16(a1, b1, acc[1][1], 0, 0, 0);
  }

  // epilogue: transpose via LDS, kc-blocked coalesced stores + fused stats
  ushort* tb = (ushort*)ldsraw;
  float*  sc = (float*)(ldsraw + 256 * 144);
  #pragma unroll
  for (int mt = 0; mt < 2; ++mt)
    #pragma unroll
    for (int nt = 0; nt < 2; ++nt){
      const int pxl = (2*wid + nt) * 32 + ln;
      #pragma unroll
      for (int rq = 0; rq < 4; ++rq){
        const int oc0 = mt*32 + 8*rq + 4*half;
        #pragma unroll
        for (int k = 0; k < 2; ++k){
          const int r = rq*4 + k*2;
          unsigned pk = (unsigned)f2b(acc[mt][nt][r]) | ((unsigned)f2b(acc[mt][nt][r+1]) << 16);
          *(unsigned*)&tb[pxl * 72 + oc0 + k*2] = pk;
        }
      }
    }
  #pragma unroll
  for (int mt = 0; mt < 2; ++mt)
    #pragma unroll
    for (int rq = 0; rq < 4; ++rq)
      #pragma unroll
      for (int t = 0; t < 4; ++t){
        const int r = rq*4 + t;
        float v  = acc[mt][0][r] + acc[mt][1][r];
        float v2 = acc[mt][0][r]*acc[mt][0][r] + acc[mt][1][r]*acc[mt][1][r];
        #pragma unroll
        for (int o = 1; o < 32; o <<= 1){ v += __shfl_xor(v, o, 64); v2 += __shfl_xor(v2, o, 64); }
        if (ln == 0){
          const int oc = mt*32 + 8*rq + 4*half + t;
          sc[(wid*CH + oc)*2] = v; sc[(wid*CH + oc)*2 + 1] = v2;
        }
      }
  __syncthreads();
  {
    const int px = lane & 31, h2 = lane >> 5;
    #pragma unroll
    for (int nt = 0; nt < 2; ++nt){
      const int rr = 2*wid + nt;
      const int p = px0 + rr*32 + px;
      const int y = p / SL, x = p - y * SL;
      #pragma unroll
      for (int h = 0; h < 2; ++h){
        const int kc = h2*2 + h;
        const ushort* sp = &tb[(rr*32 + px) * 72 + kc*16];
        ushort* dp = &out[((size_t)((y*4 + kc) * SL) + x) * 16];
        *(short8*)&dp[0] = *(const short8*)&sp[0];
        *(short8*)&dp[8] = *(const short8*)&sp[8];
      }
    }
  }
  if (tid < CH){
    float sm = 0.f, ss = 0.f;
    #pragma unroll
    for (int w = 0; w < 4; ++w){ sm += sc[(w*CH + tid)*2]; ss += sc[(w*CH + tid)*2 + 1]; }
    part[((size_t)tid * NBLK + blockIdx.x) * 2]     = sm;
    part[((size_t)tid * NBLK + blockIdx.x) * 2 + 1] = ss;
  }
}

// ---------------- norm + residual; X fp32 NCHW (d_out), Xb bf16 kc-blocked ----------
__global__ __launch_bounds__(256) void norm_res_k(const ushort* __restrict__ src,
                                                  const float* __restrict__ a,
                                                  const float* __restrict__ b,
                                                  float* __restrict__ X,
                                                  ushort* __restrict__ Xb,
                                                  int doRes){
  __shared__ float tf[64 * 68];
  const int tid = threadIdx.x;
  const int p0 = blockIdx.x * 64;
  const int y0 = p0 / SL, x0 = p0 - y0 * SL;    // 64 | 384: block stays in one row
  const int pxl = tid >> 2, kc = tid & 3, c0 = kc * 16;
  {
    const ushort* sp = &src[((size_t)((y0*4 + kc) * SL) + x0 + pxl) * 16];
    short8 v0 = *(const short8*)&sp[0], v1 = *(const short8*)&sp[8];
    #pragma unroll
    for (int k = 0; k < 8; ++k){
      tf[(c0+k)*68 + pxl]   = lrelu(b2f((ushort)v0[k]) * a[c0+k]   + b[c0+k]);
      tf[(c0+8+k)*68 + pxl] = lrelu(b2f((ushort)v1[k]) * a[c0+8+k] + b[c0+8+k]);
    }
  }
  __syncthreads();
  {
    const int c = tid >> 2, part = tid & 3;
    const size_t gb = (size_t)c * N2 + p0 + part * 16;
    float w[16];
    #pragma unroll
    for (int k = 0; k < 16; ++k) w[k] = tf[c*68 + part*16 + k];
    if (doRes){
      #pragma unroll
      for (int k = 0; k < 16; ++k) w[k] += X[gb + k];
      #pragma unroll
      for (int k = 0; k < 16; ++k) tf[c*68 + part*16 + k] = w[k];
    }
    #pragma unroll
    for (int k = 0; k < 16; ++k) X[gb + k] = w[k];
  }
  if (Xb){
    __syncthreads();
    ushort o[16];
    #pragma unroll
    for (int k = 0; k < 16; ++k) o[k] = f2b(tf[(c0+k)*68 + pxl]);
    ushort* xp = &Xb[((size_t)((y0*4 + kc) * SL) + x0 + pxl) * 16];
    *(short8*)&xp[0] = *(short8*)&o[0];
    *(short8*)&xp[8] = *(short8*)&o[8];
  }
}

// conv weights [conv][oc][ic][3][3] fp32 -> bf16 [conv][tap][kc][half][oc][8j]
__global__ void wt_k(const float* __restrict__ w, ushort* __restrict__ wt){
  const int i = blockIdx.x * 256 + threadIdx.x;   // 368640
  const int j    = i & 7;
  const int oc   = (i >> 3) & 63;
  const int half = (i >> 9) & 1;
  const int kc   = (i >> 10) & 3;
  const int tap  = (i / 4096) % 9;
  const int cv   = i / 36864;
  const int ic   = kc * 16 + half * 8 + j;
  wt[i] = f2b(w[((size_t)(cv * CH + oc) * CH + ic) * 9 + tap]);
}

// ---------------- LDS-staged MFMA conv, direct-store epilogue -------------------
// 2-phase staging (2 kc per phase) keeps LDS small; output written straight from
// the accumulator as 8B packs (4 consecutive oc) -> no epilogue transpose buffer.
template<int DIL, bool FUSE>
__global__ __launch_bounds__(256, 4) void convd_k(const ushort* __restrict__ in,
                                                  const ushort* __restrict__ wg,
                                                  const float* __restrict__ na,
                                                  const float* __restrict__ nb,
                                                  ushort* __restrict__ out,
                                                  float* __restrict__ part){
  constexpr int TH = TY + 2 * DIL;
  constexpr int TW = TX + 2 * DIL;
  constexpr int KCP = 2;               // kc per phase
  constexpr int PHASES = 2;
  __shared__ __align__(16) unsigned char ldsraw[KCP * TH * TW * 32];
  __shared__ float sc[4 * CH * 2];

  const int tid = threadIdx.x, lane = tid & 63, wid = tid >> 6;
  const int ln = lane & 31, half = lane >> 5;
  const int bx = blockIdx.x % (SL / TX), by = blockIdx.x / (SL / TX);

  floatx16 acc[2][2];
  #pragma unroll
  for (int mt = 0; mt < 2; ++mt)
    #pragma unroll
    for (int nt = 0; nt < 2; ++nt)
      #pragma unroll
      for (int r = 0; r < 16; ++r) acc[mt][nt][r] = 0.f;

  #pragma unroll
  for (int ph = 0; ph < PHASES; ++ph){
    if (ph) __syncthreads();             // all waves done reading previous phase
    // ---- stage tile (halo, zeros OOB), coalesced 16B pieces
    constexpr int PIECES = KCP * TH * TW * 2;
    for (int t = tid; t < PIECES; t += 256){
      const int half_ = t & 1;
      const int idx   = t >> 1;                 // (kcl*TH + ry)*TW + rx
      const int rx    = idx % TW;
      const int rem   = idx / TW;
      const int ry    = rem % TH;
      const int kcl   = rem / TH;
      const int kc    = ph * KCP + kcl;
      const int gy    = by * TY - DIL + ry;
      const int gx    = bx * TX - DIL + rx;
      const unsigned byteoff = ((unsigned)t * 16) ^ (((rx >> 2) & 1) << 4);
      short8 v = {0,0,0,0,0,0,0,0};
      if ((unsigned)gy < (unsigned)SL && (unsigned)gx < (unsigned)SL){
        v = *(const short8*)&in[(((size_t)(gy * 4 + kc)) * SL + gx) * 16 + half_ * 8];
        if (FUSE){
          const int c0 = kc * 16 + half_ * 8;
          float4 a0 = *(const float4*)&na[c0], a1 = *(const float4*)&na[c0 + 4];
          float4 b0 = *(const float4*)&nb[c0], b1 = *(const float4*)&nb[c0 + 4];
          ushort o[8];
          o[0] = f2b(lrelu(b2f((ushort)v[0]) * a0.x + b0.x));
          o[1] = f2b(lrelu(b2f((ushort)v[1]) * a0.y + b0.y));
          o[2] = f2b(lrelu(b2f((ushort)v[2]) * a0.z + b0.z));
          o[3] = f2b(lrelu(b2f((ushort)v[3]) * a0.w + b0.w));
          o[4] = f2b(lrelu(b2f((ushort)v[4]) * a1.x + b1.x));
          o[5] = f2b(lrelu(b2f((ushort)v[5]) * a1.y + b1.y));
          o[6] = f2b(lrelu(b2f((ushort)v[6]) * a1.z + b1.z));
          o[7] = f2b(lrelu(b2f((ushort)v[7]) * a1.w + b1.w));
          v = *(short8*)o;
        }
      }
      *(short8*)(ldsraw + byteoff) = v;
    }
    __syncthreads();
    // ---- compute from LDS
    #pragma unroll
    for (int tap = 0; tap < 9; ++tap){
      const int dy = (tap / 3 - 1) * DIL, dx = (tap % 3 - 1) * DIL;
      const int ry0 = 2 * wid + dy + DIL;
      const int rx  = ln + dx + DIL;
      const unsigned swz = ((unsigned)((rx >> 2) & 1)) << 4;
      #pragma unroll
      for (int kcl = 0; kcl < KCP; ++kcl){
        const int kc = ph * KCP + kcl;
        const ushort* ab = wg + ((size_t)((tap * 4 + kc) * 2 + half)) * 512;
        short8 a0 = *(const short8*)&ab[ln * 8];
        short8 a1 = *(const short8*)&ab[256 + ln * 8];
        const unsigned bo0 = ((unsigned)((((kcl * TH + ry0) * TW + rx) * 2 + half) * 16)) ^ swz;
        const unsigned bo1 = ((unsigned)((((kcl * TH + ry0 + 1) * TW + rx) * 2 + half) * 16)) ^ swz;
        short8 b0 = *(const short8*)(ldsraw + bo0);
        short8 b1 = *(const short8*)(ldsraw + bo1);
        acc[0][0] = __builtin_amdgcn_mfma_f32_32x32x16_bf16(a0, b0, acc[0][0], 0, 0, 0);
        acc[1][0] = __builtin_amdgcn_mfma_f32_32x32x16_bf16(a1, b0, acc[1][0], 0, 0, 0);
        acc[0][1] = __builtin_amdgcn_mfma_f32_32x32x16_bf16(a0, b1, acc[0][1], 0, 0, 0);
        acc[1][1] = __builtin_amdgcn_mfma_f32_32x32x16_bf16(a1, b1, acc[1][1], 0, 0, 0);
      }
    }
  }

  // ---- epilogue: direct 8B stores from accumulator (4 consecutive oc per pack)
  {
    const int gx = bx * TX + ln;
    #pragma unroll
    for (int nt = 0; nt < 2; ++nt){
      const int gy = by * TY + 2 * wid + nt;
      #pragma unroll
      for (int mt = 0; mt < 2; ++mt)
        #pragma unroll
        for (int rq = 0; rq < 4; ++rq){
          const int oc0 = mt * 32 + 8 * rq + 4 * half;
          const int kc = oc0 >> 4, off = oc0 & 15;
          const int r = rq * 4;
          uint2 pk;
          pk.x = (unsigned)f2b(acc[mt][nt][r])     | ((unsigned)f2b(acc[mt][nt][r+1]) << 16);
          pk.y = (unsigned)f2b(acc[mt][nt][r+2])   | ((unsigned)f2b(acc[mt][nt][r+3]) << 16);
          *(uint2*)&out[((size_t)(gy * 4 + kc) * SL + gx) * 16 + off] = pk;
        }
    }
  }
  // ---- fused stats
  #pragma unroll
  for (int mt = 0; mt < 2; ++mt)
    #pragma unroll
    for (int rq = 0; rq < 4; ++rq)
      #pragma unroll
      for (int t = 0; t < 4; ++t){
        const int r = rq*4 + t;
        float v  = acc[mt][0][r] + acc[mt][1][r];
        float v2 = acc[mt][0][r]*acc[mt][0][r] + acc[mt][1][r]*acc[mt][1][r];
        #pragma unroll
        for (int o = 1; o < 32; o <<= 1){ v += __shfl_xor(v, o, 64); v2 += __shfl_xor(v2, o, 64); }
        if (ln == 0){
          const int oc = mt*32 + 8*rq + 4*half + t;
          sc[(wid*CH + oc)*2] = v; sc[(wid*CH + oc)*2 + 1] = v2;
        }
      }
  __syncthreads();
  if (tid < CH){
    float sm = 0.f, ss = 0.f;
    #pragma unroll
    for (int w = 0; w < 4; ++w){ sm += sc[(w*CH + tid)*2]; ss += sc[(w*CH + tid)*2 + 1]; }
    part[((size_t)tid * NBLK + blockIdx.x) * 2]     = sm;
    part[((size_t)tid * NBLK + blockIdx.x) * 2 + 1] = ss;
  }
}

static void launch_conv(int dil, bool fuse, const ushort* src, const ushort* wgl,
                        const float* na, const float* nb,
                        ushort* dst, float* part, hipStream_t s){
  if (fuse){
    switch (dil){
      case 1:  convd_k<1,true><<<NBLK, 256, 0, s>>>(src, wgl, na, nb, dst, part); break;
      case 2:  convd_k<2,true><<<NBLK, 256, 0, s>>>(src, wgl, na, nb, dst, part); break;
      default: convd_k<4,true><<<NBLK, 256, 0, s>>>(src, wgl, na, nb, dst, part); break;
    }
  } else {
    switch (dil){
      case 1:  convd_k<1,false><<<NBLK, 256, 0, s>>>(src, wgl, na, nb, dst, part); break;
      case 2:  convd_k<2,false><<<NBLK, 256, 0, s>>>(src, wgl, na, nb, dst, part); break;
      default: convd_k<4,false><<<NBLK, 256, 0, s>>>(src, wgl, na, nb, dst, part); break;
    }
  }
}

extern "C" void kernel_launch(void* const* d_in, const int* in_sizes, int n_in,
                              void* d_out, int out_size, void* d_ws, size_t ws_size,
                              hipStream_t stream){
  const float* x1d    = (const float*)d_in[0];
  const float* x2     = (const float*)d_in[1];
  const float* W1     = (const float*)d_in[2];
  const float* g1     = (const float*)d_in[3];
  const float* b1     = (const float*)d_in[4];
  const float* W2     = (const float*)d_in[5];
  const float* res_w  = (const float*)d_in[11];
  const float* res_g  = (const float*)d_in[13];
  const float* res_be = (const float*)d_in[14];
  float* X = (float*)d_out;                        // fp32 NCHW residual stream

  unsigned char* wp = (unsigned char*)d_ws;
  ushort* A   = (ushort*)wp; wp += (size_t)N2 * 64 * 2;
  ushort* Bb  = (ushort*)wp; wp += (size_t)N2 * 64 * 2;
  ushort* Xb  = (ushort*)wp; wp += (size_t)N2 * 64 * 2;
  ushort* x2b = (ushort*)wp; wp += (size_t)KG2 * N2 * 16 * 2;
  ushort* wt  = (ushort*)wp; wp += (size_t)368640 * 2;
  ushort* w3b = (ushort*)wp; wp += (size_t)8192 * 2;
  ushort* w2b = (ushort*)wp; wp += (size_t)14336 * 2;
  float* fw = (float*)wp;
  float* rcP  = fw; fw += 4 * 2 * CH * SL;
  float* rowT = fw; fw += SL * CH;
  float* colT = fw; fw += SL * CH;
  float* s1m  = fw; fw += D1;   float* s1r = fw; fw += D1;
  float* s2m  = fw; fw += 256;  float* s2r = fw; fw += 256;
  float* m1   = fw; fw += 64;   float* rs1 = fw; fw += 64;
  float* aA   = fw; fw += 64;   float* bA  = fw; fw += 64;
  float* aB   = fw; fw += 64;   float* bB  = fw; fw += 64;
  float* part = fw; fw += (size_t)D2 * NBLK * 2;   // covers both stats shapes

  // ---- 1d branch
  stats_k<<<dim3(1, D1), 256, 0, stream>>>(x1d, SL, part);
  stats_final_k<<<13, 1024, 0, stream>>>(part, D1, 1, 1.f / SL, s1m, s1r);
  rowcol_k<<<dim3(2 * CH * SL / 256, 4), 256, 0, stream>>>(x1d, W1, s1r, rcP);
  rowcol_stats_k<<<CH, 256, 0, stream>>>(rcP, m1, rs1);
  rowcolT_k<<<SL * CH / 256, 256, 0, stream>>>(rcP, m1, rs1, g1, b1, rowT, colT);
  pair1n_k<<<N2 * 64 / 4096, 256, 0, stream>>>(rowT, colT, A);

  // ---- 2d branch: fused convert+stats -> MFMA GEMM
  x2cvt_k<<<dim3(XCHUNK, KG2), 256, 0, stream>>>(x2, x2b, part);
  stats_final_k<<<4, 1024, 0, stream>>>(part, D2, XCHUNK, 1.f / N2, s2m, s2r);
  w2b_k<<<56, 256, 0, stream>>>(W2, s2r, w2b);
  pair2m_k<<<NBLK, 256, 0, stream>>>(x2b, w2b, Bb, part);
  statsaffine_k<<<1, 1024, 0, stream>>>(part, NBLK, 1.f / N2,
      (const float*)d_in[6], (const float*)d_in[7], 0, aA, bA);
  norm_nhwc_k<<<N2 * 64 / 4096, 256, 0, stream>>>(Bb, aA, bA);

  // ---- mix (MFMA, in-place over A) + bootstrap X
  w3b_k<<<32, 256, 0, stream>>>((const float*)d_in[8], w3b);
  mixm_k<<<NBLK, 256, 0, stream>>>(A, Bb, w3b, A, part);
  statsaffine_k<<<1, 1024, 0, stream>>>(part, NBLK, 1.f / N2,
      (const float*)d_in[9], (const float*)d_in[10], 0, aA, bA);
  norm_res_k<<<N2 / 64, 256, 0, stream>>>(A, aA, bA, X, Xb, 0);

  // ---- conv weights
  wt_k<<<368640 / 256, 256, 0, stream>>>(res_w, wt);

  // ---- 5 residual layers x 2 convs (norm between convs fused into conv2 staging)
  const int dil[5] = {1, 2, 4, 2, 1};
  for (int layer = 0; layer < 5; ++layer){
    const int d = dil[layer];
    const int li0 = layer * 2, li1 = li0 + 1;
    launch_conv(d, false, Xb, wt + (size_t)li0 * 36864, nullptr, nullptr, A, part, stream);
    statsaffine_k<<<1, 1024, 0, stream>>>(part, NBLK, 1.f / N2, res_g, res_be, li0 * CH, aA, bA);
    launch_conv(d, true, A, wt + (size_t)li1 * 36864, aA, bA, Bb, part, stream);
    statsaffine_k<<<1, 1024, 0, stream>>>(part, NBLK, 1.f / N2, res_g, res_be, li1 * CH, aB, bB);
    norm_res_k<<<N2 / 64, 256, 0, stream>>>(Bb, aB, bB, X,
        (layer == 4) ? nullptr : Xb, 1);
  }
}

// Round 7
// 995.490 us; speedup vs baseline: 1.0450x; 1.0110x over previous
//
#include <hip/hip_runtime.h>
#include <hip/hip_bf16.h>

typedef __attribute__((ext_vector_type(8)))  short short8;
typedef __attribute__((ext_vector_type(16))) float floatx16;
typedef unsigned short ushort;

constexpr int SL  = 384;
constexpr int N2  = SL * SL;      // 147456
constexpr int CH  = 64;
constexpr int D1  = 788;
constexpr int D2  = 210;
constexpr int KG2 = 14;           // ceil(D2/16)
constexpr float EPSF = 1e-5f;

constexpr int TX = 32, TY = 8;
constexpr int NBLK = (SL / TX) * (SL / TY);   // 576
constexpr int XCHUNK = 72;                     // x2cvt blocks in px dim

// ---- activation layout ("kc-blocked NHWC"):
//   record R = (y*4 + kc)*SL + x holds channels [kc*16, kc*16+16) as 16 bf16 (32B).

__device__ __forceinline__ float lrelu(float v){ return v >= 0.f ? v : 0.01f * v; }
__device__ __forceinline__ ushort f2b(float f){
  __hip_bfloat16 h = __float2bfloat16(f); return *(ushort*)&h;
}
__device__ __forceinline__ float b2f(ushort u){
  __hip_bfloat16 h = *(__hip_bfloat16*)&u; return __bfloat162float(h);
}

__device__ __forceinline__ float wred(float v){
  #pragma unroll
  for (int o = 32; o; o >>= 1) v += __shfl_down(v, o, 64);
  return v;
}

// ---------------- per-channel stats over fp32 NCHW (x1d only) ----------------
__global__ void stats_k(const float* __restrict__ x, int n, float* __restrict__ part){
  const int c = blockIdx.y, s = blockIdx.x, S = gridDim.x;
  const int chunk = (n + S - 1) / S;
  const int st = s * chunk, en = min(n, st + chunk);
  const float* p = x + (size_t)c * n;
  float sm = 0.f, ss = 0.f;
  for (int i = st + threadIdx.x; i < en; i += blockDim.x){
    float v = p[i]; sm += v; ss += v * v;
  }
  sm = wred(sm); ss = wred(ss);
  __shared__ float aux[8];
  const int wid = threadIdx.x >> 6, lane = threadIdx.x & 63;
  if (lane == 0){ aux[wid] = sm; aux[4 + wid] = ss; }
  __syncthreads();
  if (threadIdx.x == 0){
    part[((size_t)c * S + s) * 2]     = aux[0] + aux[1] + aux[2] + aux[3];
    part[((size_t)c * S + s) * 2 + 1] = aux[4] + aux[5] + aux[6] + aux[7];
  }
}

// parallel finalize: 16 threads per channel, width-16 shuffle reduce
__global__ void stats_final_k(const float* __restrict__ part, int C, int S, float ninv,
                              float* __restrict__ mean, float* __restrict__ rstd){
  const int c = blockIdx.x * 64 + (threadIdx.x >> 4);
  const int t = threadIdx.x & 15;
  if (c >= C) return;
  float sm = 0.f, ss = 0.f;
  for (int s = t; s < S; s += 16){
    sm += part[((size_t)c * S + s) * 2];
    ss += part[((size_t)c * S + s) * 2 + 1];
  }
  #pragma unroll
  for (int o = 8; o; o >>= 1){ sm += __shfl_down(sm, o, 16); ss += __shfl_down(ss, o, 16); }
  if (t == 0){
    const float m = sm * ninv;
    mean[c] = m;
    rstd[c] = rsqrtf(ss * ninv - m * m + EPSF);
  }
}

// parallel stats->affine: 16 threads per channel (C=64, one 1024-thread block)
__global__ void statsaffine_k(const float* __restrict__ part, int S, float ninv,
                              const float* __restrict__ g, const float* __restrict__ be,
                              int goff, float* __restrict__ ao, float* __restrict__ bo){
  const int c = threadIdx.x >> 4;
  const int t = threadIdx.x & 15;
  float sm = 0.f, ss = 0.f;
  for (int s = t; s < S; s += 16){
    sm += part[((size_t)c * S + s) * 2];
    ss += part[((size_t)c * S + s) * 2 + 1];
  }
  #pragma unroll
  for (int o = 8; o; o >>= 1){ sm += __shfl_down(sm, o, 16); ss += __shfl_down(ss, o, 16); }
  if (t == 0){
    const float m = sm * ninv;
    const float r = rsqrtf(ss * ninv - m * m + EPSF);
    const float a = r * g[goff + c];
    ao[c] = a;
    bo[c] = be[goff + c] - m * a;
  }
}

// ---------------- 1d branch (D1 split x4 for occupancy) ----------------
__global__ void rowcol_k(const float* __restrict__ x1d, const float* __restrict__ W1,
                         const float* __restrict__ r1, float* __restrict__ rcP){
  const int idx = blockIdx.x * 256 + threadIdx.x;   // (half, c, l)
  const int chunk = blockIdx.y;
  const int half = idx / (CH * SL);
  const int rem  = idx % (CH * SL);
  const int c = rem / SL, l = rem % SL;
  const int d0 = chunk * 197, d1 = min(D1, d0 + 197);
  const float* wp = W1 + (size_t)c * (2 * D1) + (size_t)half * D1;
  float acc = 0.f;
  for (int d = d0; d < d1; ++d)
    acc += wp[d] * (x1d[(size_t)d * SL + l] * r1[d]);
  rcP[(size_t)chunk * (2 * CH * SL) + idx] = acc;
}

__global__ void rowcol_stats_k(const float* __restrict__ rcP,
                               float* __restrict__ m1, float* __restrict__ rs1){
  const int c = blockIdx.x;
  float sr = 0, ssr = 0, sc = 0, ssc = 0;
  for (int i = threadIdx.x; i < SL; i += blockDim.x){
    float r = 0, q = 0;
    #pragma unroll
    for (int k = 0; k < 4; ++k){
      r += rcP[(size_t)k * (2*CH*SL) + c * SL + i];
      q += rcP[(size_t)k * (2*CH*SL) + CH*SL + c * SL + i];
    }
    sr += r; ssr += r * r; sc += q; ssc += q * q;
  }
  sr = wred(sr); ssr = wred(ssr); sc = wred(sc); ssc = wred(ssc);
  __shared__ float aux[16];
  const int wid = threadIdx.x >> 6, lane = threadIdx.x & 63;
  if (lane == 0){ aux[wid] = sr; aux[4+wid] = ssr; aux[8+wid] = sc; aux[12+wid] = ssc; }
  __syncthreads();
  if (threadIdx.x == 0){
    float a = 0, b = 0, d = 0, e = 0;
    for (int i = 0; i < 4; ++i){ a += aux[i]; b += aux[4+i]; d += aux[8+i]; e += aux[12+i]; }
    const float mr = a / SL, mc = d / SL;
    const float vr = b / SL - mr * mr, vc = e / SL - mc * mc;
    m1[c]  = mr + mc;
    rs1[c] = rsqrtf(vr + vc + EPSF);
  }
}

__global__ void rowcolT_k(const float* __restrict__ rcP,
                          const float* __restrict__ m1, const float* __restrict__ rs1,
                          const float* __restrict__ g1, const float* __restrict__ b1,
                          float* __restrict__ rowT, float* __restrict__ colT){
  const int i = blockIdx.x * 256 + threadIdx.x;   // 384*64
  const int l = i >> 6, c = i & 63;
  float r = 0, q = 0;
  #pragma unroll
  for (int k = 0; k < 4; ++k){
    r += rcP[(size_t)k * (2*CH*SL) + c * SL + l];
    q += rcP[(size_t)k * (2*CH*SL) + CH*SL + c * SL + l];
  }
  const float a  = rs1[c] * g1[c];
  const float bb = b1[c] - m1[c] * a;
  rowT[i] = r * a + bb;
  colT[i] = q * a;
}

// pair1: one thread = one 16-ch record of the kc-blocked layout
__global__ __launch_bounds__(256) void pair1n_k(const float* __restrict__ rowT,
                                                const float* __restrict__ colT,
                                                ushort* __restrict__ out){
  const size_t q = ((size_t)blockIdx.x * 256 + threadIdx.x) * 16;
  const int R = (int)(q >> 4);
  const int x = R % SL;
  const int t = R / SL;            // y*4 + kc
  const int kc = t & 3, y = t >> 2;
  const int c0 = kc * 16;
  const float4* rp = (const float4*)&rowT[y * 64 + c0];
  const float4* cp = (const float4*)&colT[x * 64 + c0];
  ushort o[16];
  #pragma unroll
  for (int k = 0; k < 4; ++k){
    float4 r = rp[k], cl = cp[k];
    o[4*k]   = f2b(lrelu(r.x + cl.x));
    o[4*k+1] = f2b(lrelu(r.y + cl.y));
    o[4*k+2] = f2b(lrelu(r.z + cl.z));
    o[4*k+3] = f2b(lrelu(r.w + cl.w));
  }
  *(short8*)&out[q]     = *(short8*)&o[0];
  *(short8*)&out[q + 8] = *(short8*)&o[8];
}

// ---------------- 2d branch: fused convert+stats, then MFMA GEMM ----------------
__global__ __launch_bounds__(256, 2) void x2cvt_k(const float* __restrict__ x2,
                                                  ushort* __restrict__ x2b,
                                                  float* __restrict__ part){
  const int g   = blockIdx.y;            // d-group 0..13
  const int tid = threadIdx.x;
  const int d0  = g * 16;
  float sm[16], ss[16];
  #pragma unroll
  for (int i = 0; i < 16; ++i){ sm[i] = 0.f; ss[i] = 0.f; }
  #pragma unroll
  for (int it = 0; it < 4; ++it){
    const int p = blockIdx.x * 2048 + it * 512 + tid * 2;
    float2 v[16];
    #pragma unroll
    for (int i = 0; i < 16; ++i){
      const int d = d0 + i;
      if (d < D2) v[i] = *(const float2*)&x2[(size_t)d * N2 + p];
      else        v[i] = make_float2(0.f, 0.f);
    }
    ushort o[32];
    #pragma unroll
    for (int i = 0; i < 16; ++i){
      o[i]      = f2b(v[i].x);
      o[16 + i] = f2b(v[i].y);
      sm[i] += v[i].x + v[i].y;
      ss[i] += v[i].x * v[i].x + v[i].y * v[i].y;
    }
    ushort* dp = &x2b[((size_t)g * N2 + p) * 16];
    *(short8*)&dp[0]  = *(short8*)&o[0];
    *(short8*)&dp[8]  = *(short8*)&o[8];
    *(short8*)&dp[16] = *(short8*)&o[16];
    *(short8*)&dp[24] = *(short8*)&o[24];
  }
  __shared__ float aux[4][16][2];
  const int wid = tid >> 6, lane = tid & 63;
  #pragma unroll
  for (int i = 0; i < 16; ++i){
    float a = wred(sm[i]), b = wred(ss[i]);
    if (lane == 0){ aux[wid][i][0] = a; aux[wid][i][1] = b; }
  }
  __syncthreads();
  if (tid < 16){
    const int d = d0 + tid;
    if (d < D2){
      float a = aux[0][tid][0] + aux[1][tid][0] + aux[2][tid][0] + aux[3][tid][0];
      float b = aux[0][tid][1] + aux[1][tid][1] + aux[2][tid][1] + aux[3][tid][1];
      part[((size_t)d * XCHUNK + blockIdx.x) * 2]     = a;
      part[((size_t)d * XCHUNK + blockIdx.x) * 2 + 1] = b;
    }
  }
}

// W2 [oc][D2] fp32 * r2 -> bf16 A-fragment layout [kc(14)*2+half][oc(64)][j(8)]
__global__ void w2b_k(const float* __restrict__ W2, const float* __restrict__ r2,
                      ushort* __restrict__ w2b){
  const int i = blockIdx.x * 256 + threadIdx.x;   // 14336
  const int j    = i & 7;
  const int oc   = (i >> 3) & 63;
  const int half = (i >> 9) & 1;
  const int kc   = i >> 10;
  const int d    = kc * 16 + half * 8 + j;
  w2b[i] = (d < D2) ? f2b(W2[(size_t)oc * D2 + d] * r2[d]) : (ushort)0;
}

// MFMA GEMM: out[oc][px] = sum_d w2e[oc][d] * x2[d][px], K=224 (padded)
__global__ __launch_bounds__(256) void pair2m_k(const ushort* __restrict__ x2b,
                                                const ushort* __restrict__ w2b,
                                                ushort* __restrict__ out,
                                                float* __restrict__ part){
  __shared__ __align__(16) unsigned char ldsraw[256 * 144 + 4 * CH * 2 * 4];
  const int tid = threadIdx.x, lane = tid & 63, wid = tid >> 6;
  const int ln = lane & 31, half = lane >> 5;
  const int px0 = blockIdx.x * 256;
  floatx16 acc[2][2];
  #pragma unroll
  for (int mt = 0; mt < 2; ++mt)
    #pragma unroll
    for (int nt = 0; nt < 2; ++nt)
      #pragma unroll
      for (int r = 0; r < 16; ++r) acc[mt][nt][r] = 0.f;

  const int p0w = px0 + wid * 64 + ln;
  #pragma unroll
  for (int kc = 0; kc < KG2; ++kc){
    const ushort* ab = w2b + ((size_t)(kc * 2 + half)) * 512;
    short8 a0 = *(const short8*)&ab[ln * 8];
    short8 a1 = *(const short8*)&ab[256 + ln * 8];
    short8 b0 = *(const short8*)&x2b[((size_t)kc * N2 + p0w) * 16 + half * 8];
    short8 b1 = *(const short8*)&x2b[((size_t)kc * N2 + p0w + 32) * 16 + half * 8];
    acc[0][0] = __builtin_amdgcn_mfma_f32_32x32x16_bf16(a0, b0, acc[0][0], 0, 0, 0);
    acc[1][0] = __builtin_amdgcn_mfma_f32_32x32x16_bf16(a1, b0, acc[1][0], 0, 0, 0);
    acc[0][1] = __builtin_amdgcn_mfma_f32_32x32x16_bf16(a0, b1, acc[0][1], 0, 0, 0);
    acc[1][1] = __builtin_amdgcn_mfma_f32_32x32x16_bf16(a1, b1, acc[1][1], 0, 0, 0);
  }

  // epilogue: transpose via LDS, kc-blocked coalesced stores + fused stats
  ushort* tb = (ushort*)ldsraw;
  float*  sc = (float*)(ldsraw + 256 * 144);
  #pragma unroll
  for (int mt = 0; mt < 2; ++mt)
    #pragma unroll
    for (int nt = 0; nt < 2; ++nt){
      const int pxl = (2*wid + nt) * 32 + ln;
      #pragma unroll
      for (int rq = 0; rq < 4; ++rq){
        const int oc0 = mt*32 + 8*rq + 4*half;
        #pragma unroll
        for (int k = 0; k < 2; ++k){
          const int r = rq*4 + k*2;
          unsigned pk = (unsigned)f2b(acc[mt][nt][r]) | ((unsigned)f2b(acc[mt][nt][r+1]) << 16);
          *(unsigned*)&tb[pxl * 72 + oc0 + k*2] = pk;
        }
      }
    }
  #pragma unroll
  for (int mt = 0; mt < 2; ++mt)
    #pragma unroll
    for (int rq = 0; rq < 4; ++rq)
      #pragma unroll
      for (int t = 0; t < 4; ++t){
        const int r = rq*4 + t;
        float v  = acc[mt][0][r] + acc[mt][1][r];
        float v2 = acc[mt][0][r]*acc[mt][0][r] + acc[mt][1][r]*acc[mt][1][r];
        #pragma unroll
        for (int o = 1; o < 32; o <<= 1){ v += __shfl_xor(v, o, 64); v2 += __shfl_xor(v2, o, 64); }
        if (ln == 0){
          const int oc = mt*32 + 8*rq + 4*half + t;
          sc[(wid*CH + oc)*2] = v; sc[(wid*CH + oc)*2 + 1] = v2;
        }
      }
  __syncthreads();
  {
    const int px = lane & 31, h2 = lane >> 5;
    #pragma unroll
    for (int nt = 0; nt < 2; ++nt){
      const int rr = 2*wid + nt;
      const int p = px0 + rr*32 + px;
      const int y = p / SL, x = p - y * SL;
      #pragma unroll
      for (int h = 0; h < 2; ++h){
        const int kc = h2*2 + h;
        const ushort* sp = &tb[(rr*32 + px) * 72 + kc*16];
        ushort* dp = &out[((size_t)((y*4 + kc) * SL) + x) * 16];
        *(short8*)&dp[0] = *(const short8*)&sp[0];
        *(short8*)&dp[8] = *(const short8*)&sp[8];
      }
    }
  }
  if (tid < CH){
    float sm = 0.f, ss = 0.f;
    #pragma unroll
    for (int w = 0; w < 4; ++w){ sm += sc[(w*CH + tid)*2]; ss += sc[(w*CH + tid)*2 + 1]; }
    part[((size_t)tid * NBLK + blockIdx.x) * 2]     = sm;
    part[((size_t)tid * NBLK + blockIdx.x) * 2 + 1] = ss;
  }
}

// affine+leaky in place over kc-blocked layout (one thread = one 16-ch record)
__global__ __launch_bounds__(256) void norm_nhwc_k(ushort* __restrict__ x,
                                                   const float* __restrict__ a,
                                                   const float* __restrict__ b){
  const size_t q = ((size_t)blockIdx.x * 256 + threadIdx.x) * 16;
  const int R = (int)(q >> 4);
  const int c0 = ((R / SL) & 3) * 16;
  short8 v0 = *(short8*)&x[q], v1 = *(short8*)&x[q + 8];
  ushort o[16];
  #pragma unroll
  for (int k = 0; k < 8; ++k){
    o[k]   = f2b(lrelu(b2f((ushort)v0[k]) * a[c0+k]   + b[c0+k]));
    o[k+8] = f2b(lrelu(b2f((ushort)v1[k]) * a[c0+8+k] + b[c0+8+k]));
  }
  *(short8*)&x[q]     = *(short8*)&o[0];
  *(short8*)&x[q + 8] = *(short8*)&o[8];
}

// W3 [c][2CH] fp32 -> bf16 A-operand layout [kc(8)][half(2)][oc(64)][j(8)]
__global__ void w3b_k(const float* __restrict__ W3, ushort* __restrict__ w3b){
  const int i = blockIdx.x * 256 + threadIdx.x;   // 8192
  const int j    = i & 7;
  const int oc   = (i >> 3) & 63;
  const int half = (i >> 9) & 1;
  const int kc   = i >> 10;
  const int e    = kc * 16 + half * 8 + j;
  w3b[i] = f2b(W3[oc * (2 * CH) + e]);
}

// ---------------- MFMA mix: K=128 (A || Bb), coalesced kc-blocked B loads ----------
__global__ __launch_bounds__(256) void mixm_k(const ushort* __restrict__ A,
                                              const ushort* __restrict__ Bv,
                                              const ushort* __restrict__ w3b,
                                              ushort* __restrict__ out,
                                              float* __restrict__ part){
  __shared__ __align__(16) unsigned char ldsraw[256 * 144 + 4 * CH * 2 * 4];
  const int tid = threadIdx.x, lane = tid & 63, wid = tid >> 6;
  const int ln = lane & 31, half = lane >> 5;
  const int px0 = blockIdx.x * 256;
  floatx16 acc[2][2];
  #pragma unroll
  for (int mt = 0; mt < 2; ++mt)
    #pragma unroll
    for (int nt = 0; nt < 2; ++nt)
      #pragma unroll
      for (int r = 0; r < 16; ++r) acc[mt][nt][r] = 0.f;

  const int p0w = px0 + wid * 64 + ln;
  const int p1w = p0w + 32;
  const int y0 = p0w / SL, x0 = p0w - y0 * SL;
  const int y1 = p1w / SL, x1 = p1w - y1 * SL;
  #pragma unroll
  for (int kc = 0; kc < 8; ++kc){
    const ushort* src = (kc < 4) ? A : Bv;
    const int kcm = kc & 3;
    const ushort* ab = w3b + ((size_t)(kc * 2 + half)) * 512;
    short8 a0 = *(const short8*)&ab[ln * 8];
    short8 a1 = *(const short8*)&ab[256 + ln * 8];
    const size_t r0 = ((size_t)((y0 * 4 + kcm) * SL) + x0) * 16 + half * 8;
    const size_t r1 = ((size_t)((y1 * 4 + kcm) * SL) + x1) * 16 + half * 8;
    short8 b0 = *(const short8*)&src[r0];
    short8 b1 = *(const short8*)&src[r1];
    acc[0][0] = __builtin_amdgcn_mfma_f32_32x32x16_bf16(a0, b0, acc[0][0], 0, 0, 0);
    acc[1][0] = __builtin_amdgcn_mfma_f32_32x32x16_bf16(a1, b0, acc[1][0], 0, 0, 0);
    acc[0][1] = __builtin_amdgcn_mfma_f32_32x32x16_bf16(a0, b1, acc[0][1], 0, 0, 0);
    acc[1][1] = __builtin_amdgcn_mfma_f32_32x32x16_bf16(a1, b1, acc[1][1], 0, 0, 0);
  }

  // epilogue: transpose via LDS, kc-blocked coalesced stores + fused stats
  ushort* tb = (ushort*)ldsraw;
  float*  sc = (float*)(ldsraw + 256 * 144);
  #pragma unroll
  for (int mt = 0; mt < 2; ++mt)
    #pragma unroll
    for (int nt = 0; nt < 2; ++nt){
      const int pxl = (2*wid + nt) * 32 + ln;
      #pragma unroll
      for (int rq = 0; rq < 4; ++rq){
        const int oc0 = mt*32 + 8*rq + 4*half;
        #pragma unroll
        for (int k = 0; k < 2; ++k){
          const int r = rq*4 + k*2;
          unsigned pk = (unsigned)f2b(acc[mt][nt][r]) | ((unsigned)f2b(acc[mt][nt][r+1]) << 16);
          *(unsigned*)&tb[pxl * 72 + oc0 + k*2] = pk;
        }
      }
    }
  #pragma unroll
  for (int mt = 0; mt < 2; ++mt)
    #pragma unroll
    for (int rq = 0; rq < 4; ++rq)
      #pragma unroll
      for (int t = 0; t < 4; ++t){
        const int r = rq*4 + t;
        float v  = acc[mt][0][r] + acc[mt][1][r];
        float v2 = acc[mt][0][r]*acc[mt][0][r] + acc[mt][1][r]*acc[mt][1][r];
        #pragma unroll
        for (int o = 1; o < 32; o <<= 1){ v += __shfl_xor(v, o, 64); v2 += __shfl_xor(v2, o, 64); }
        if (ln == 0){
          const int oc = mt*32 + 8*rq + 4*half + t;
          sc[(wid*CH + oc)*2] = v; sc[(wid*CH + oc)*2 + 1] = v2;
        }
      }
  __syncthreads();
  {
    const int px = lane & 31, h2 = lane >> 5;
    #pragma unroll
    for (int nt = 0; nt < 2; ++nt){
      const int rr = 2*wid + nt;
      const int p = px0 + rr*32 + px;
      const int y = p / SL, x = p - y * SL;
      #pragma unroll
      for (int h = 0; h < 2; ++h){
        const int kc = h2*2 + h;
        const ushort* sp = &tb[(rr*32 + px) * 72 + kc*16];
        ushort* dp = &out[((size_t)((y*4 + kc) * SL) + x) * 16];
        *(short8*)&dp[0] = *(const short8*)&sp[0];
        *(short8*)&dp[8] = *(const short8*)&sp[8];
      }
    }
  }
  if (tid < CH){
    float sm = 0.f, ss = 0.f;
    #pragma unroll
    for (int w = 0; w < 4; ++w){ sm += sc[(w*CH + tid)*2]; ss += sc[(w*CH + tid)*2 + 1]; }
    part[((size_t)tid * NBLK + blockIdx.x) * 2]     = sm;
    part[((size_t)tid * NBLK + blockIdx.x) * 2 + 1] = ss;
  }
}

// ---------------- norm + residual; X fp32 NCHW (d_out), Xb bf16 kc-blocked ----------
__global__ __launch_bounds__(256) void norm_res_k(const ushort* __restrict__ src,
                                                  const float* __restrict__ a,
                                                  const float* __restrict__ b,
                                                  float* __restrict__ X,
                                                  ushort* __restrict__ Xb,
                                                  int doRes){
  __shared__ float tf[64 * 68];
  const int tid = threadIdx.x;
  const int p0 = blockIdx.x * 64;
  const int y0 = p0 / SL, x0 = p0 - y0 * SL;    // 64 | 384: block stays in one row
  const int pxl = tid >> 2, kc = tid & 3, c0 = kc * 16;
  {
    const ushort* sp = &src[((size_t)((y0*4 + kc) * SL) + x0 + pxl) * 16];
    short8 v0 = *(const short8*)&sp[0], v1 = *(const short8*)&sp[8];
    #pragma unroll
    for (int k = 0; k < 8; ++k){
      tf[(c0+k)*68 + pxl]   = lrelu(b2f((ushort)v0[k]) * a[c0+k]   + b[c0+k]);
      tf[(c0+8+k)*68 + pxl] = lrelu(b2f((ushort)v1[k]) * a[c0+8+k] + b[c0+8+k]);
    }
  }
  __syncthreads();
  {
    const int c = tid >> 2, part = tid & 3;
    const size_t gb = (size_t)c * N2 + p0 + part * 16;
    float w[16];
    #pragma unroll
    for (int k = 0; k < 16; ++k) w[k] = tf[c*68 + part*16 + k];
    if (doRes){
      #pragma unroll
      for (int k = 0; k < 16; ++k) w[k] += X[gb + k];
      #pragma unroll
      for (int k = 0; k < 16; ++k) tf[c*68 + part*16 + k] = w[k];
    }
    #pragma unroll
    for (int k = 0; k < 16; ++k) X[gb + k] = w[k];
  }
  if (Xb){
    __syncthreads();
    ushort o[16];
    #pragma unroll
    for (int k = 0; k < 16; ++k) o[k] = f2b(tf[(c0+k)*68 + pxl]);
    ushort* xp = &Xb[((size_t)((y0*4 + kc) * SL) + x0 + pxl) * 16];
    *(short8*)&xp[0] = *(short8*)&o[0];
    *(short8*)&xp[8] = *(short8*)&o[8];
  }
}

// conv weights [conv][oc][ic][3][3] fp32 -> bf16 [conv][tap][kc][half][oc][8j]
__global__ void wt_k(const float* __restrict__ w, ushort* __restrict__ wt){
  const int i = blockIdx.x * 256 + threadIdx.x;   // 368640
  const int j    = i & 7;
  const int oc   = (i >> 3) & 63;
  const int half = (i >> 9) & 1;
  const int kc   = (i >> 10) & 3;
  const int tap  = (i / 4096) % 9;
  const int cv   = i / 36864;
  const int ic   = kc * 16 + half * 8 + j;
  wt[i] = f2b(w[((size_t)(cv * CH + oc) * CH + ic) * 9 + tap]);
}

// ---------------- LDS-staged MFMA conv: activations AND weights in LDS ----------
// 4 single-kc phases; inner loop is pure ds_read + MFMA (no global loads).
template<int DIL, bool FUSE>
__global__ __launch_bounds__(256, 4) void convd_k(const ushort* __restrict__ in,
                                                  const ushort* __restrict__ wg,
                                                  const float* __restrict__ na,
                                                  const float* __restrict__ nb,
                                                  ushort* __restrict__ out,
                                                  float* __restrict__ part){
  constexpr int TH = TY + 2 * DIL;
  constexpr int TW = TX + 2 * DIL;
  constexpr int ACT_B = TH * TW * 32;            // 2 halves x 16B per (ry,rx)
  constexpr int W_USH = 9 * 2 * 512;             // per-kc weight slab (ushorts)
  __shared__ __align__(16) unsigned char ldsraw[ACT_B];
  __shared__ __align__(16) ushort wl[W_USH];
  __shared__ float sc[4 * CH * 2];

  const int tid = threadIdx.x, lane = tid & 63, wid = tid >> 6;
  const int ln = lane & 31, half = lane >> 5;
  const int bx = blockIdx.x % (SL / TX), by = blockIdx.x / (SL / TX);

  floatx16 acc[2][2];
  #pragma unroll
  for (int mt = 0; mt < 2; ++mt)
    #pragma unroll
    for (int nt = 0; nt < 2; ++nt)
      #pragma unroll
      for (int r = 0; r < 16; ++r) acc[mt][nt][r] = 0.f;

  #pragma unroll
  for (int kc = 0; kc < 4; ++kc){
    if (kc) __syncthreads();             // all waves done reading previous phase
    // ---- stage this kc's weight slab: 9 taps x 2 half x 512 ushorts (18.4KB)
    {
      constexpr int WPIECES = W_USH / 8;         // 16B pieces = 1152
      for (int t = tid; t < WPIECES; t += 256){
        const int th = t >> 6;                   // tap*2+half block (18)
        const int e0 = (t & 63) * 8;
        const int tap = th >> 1, hf = th & 1;
        *(short8*)&wl[t * 8] =
          *(const short8*)&wg[((size_t)((tap * 4 + kc) * 2 + hf)) * 512 + e0];
      }
    }
    // ---- stage activation tile (halo, zeros OOB), coalesced 16B pieces
    {
      constexpr int PIECES = TH * TW * 2;
      for (int t = tid; t < PIECES; t += 256){
        const int half_ = t & 1;
        const int idx   = t >> 1;                // ry*TW + rx
        const int rx    = idx % TW;
        const int ry    = idx / TW;
        const int gy    = by * TY - DIL + ry;
        const int gx    = bx * TX - DIL + rx;
        const unsigned byteoff = ((unsigned)t * 16) ^ (((rx >> 2) & 1) << 4);
        short8 v = {0,0,0,0,0,0,0,0};
        if ((unsigned)gy < (unsigned)SL && (unsigned)gx < (unsigned)SL){
          v = *(const short8*)&in[(((size_t)(gy * 4 + kc)) * SL + gx) * 16 + half_ * 8];
          if (FUSE){
            const int c0 = kc * 16 + half_ * 8;
            float4 a0 = *(const float4*)&na[c0], a1 = *(const float4*)&na[c0 + 4];
            float4 b0 = *(const float4*)&nb[c0], b1 = *(const float4*)&nb[c0 + 4];
            ushort o[8];
            o[0] = f2b(lrelu(b2f((ushort)v[0]) * a0.x + b0.x));
            o[1] = f2b(lrelu(b2f((ushort)v[1]) * a0.y + b0.y));
            o[2] = f2b(lrelu(b2f((ushort)v[2]) * a0.z + b0.z));
            o[3] = f2b(lrelu(b2f((ushort)v[3]) * a0.w + b0.w));
            o[4] = f2b(lrelu(b2f((ushort)v[4]) * a1.x + b1.x));
            o[5] = f2b(lrelu(b2f((ushort)v[5]) * a1.y + b1.y));
            o[6] = f2b(lrelu(b2f((ushort)v[6]) * a1.z + b1.z));
            o[7] = f2b(lrelu(b2f((ushort)v[7]) * a1.w + b1.w));
            v = *(short8*)o;
          }
        }
        *(short8*)(ldsraw + byteoff) = v;
      }
    }
    __syncthreads();
    // ---- compute from LDS only
    #pragma unroll
    for (int tap = 0; tap < 9; ++tap){
      const int dy = (tap / 3 - 1) * DIL, dx = (tap % 3 - 1) * DIL;
      const int ry0 = 2 * wid + dy + DIL;
      const int rx  = ln + dx + DIL;
      const unsigned swz = ((unsigned)((rx >> 2) & 1)) << 4;
      const ushort* ab = &wl[(tap * 2 + half) * 512];
      short8 a0 = *(const short8*)&ab[ln * 8];
      short8 a1 = *(const short8*)&ab[256 + ln * 8];
      const unsigned bo0 = ((unsigned)(((ry0 * TW + rx) * 2 + half) * 16)) ^ swz;
      const unsigned bo1 = ((unsigned)((((ry0 + 1) * TW + rx) * 2 + half) * 16)) ^ swz;
      short8 b0 = *(const short8*)(ldsraw + bo0);
      short8 b1 = *(const short8*)(ldsraw + bo1);
      acc[0][0] = __builtin_amdgcn_mfma_f32_32x32x16_bf16(a0, b0, acc[0][0], 0, 0, 0);
      acc[1][0] = __builtin_amdgcn_mfma_f32_32x32x16_bf16(a1, b0, acc[1][0], 0, 0, 0);
      acc[0][1] = __builtin_amdgcn_mfma_f32_32x32x16_bf16(a0, b1, acc[0][1], 0, 0, 0);
      acc[1][1] = __builtin_amdgcn_mfma_f32_32x32x16_bf16(a1, b1, acc[1][1], 0, 0, 0);
    }
  }

  // ---- epilogue: direct 8B stores from accumulator (4 consecutive oc per pack)
  {
    const int gx = bx * TX + ln;
    #pragma unroll
    for (int nt = 0; nt < 2; ++nt){
      const int gy = by * TY + 2 * wid + nt;
      #pragma unroll
      for (int mt = 0; mt < 2; ++mt)
        #pragma unroll
        for (int rq = 0; rq < 4; ++rq){
          const int oc0 = mt * 32 + 8 * rq + 4 * half;
          const int kc = oc0 >> 4, off = oc0 & 15;
          const int r = rq * 4;
          uint2 pk;
          pk.x = (unsigned)f2b(acc[mt][nt][r])     | ((unsigned)f2b(acc[mt][nt][r+1]) << 16);
          pk.y = (unsigned)f2b(acc[mt][nt][r+2])   | ((unsigned)f2b(acc[mt][nt][r+3]) << 16);
          *(uint2*)&out[((size_t)(gy * 4 + kc) * SL + gx) * 16 + off] = pk;
        }
    }
  }
  // ---- fused stats
  #pragma unroll
  for (int mt = 0; mt < 2; ++mt)
    #pragma unroll
    for (int rq = 0; rq < 4; ++rq)
      #pragma unroll
      for (int t = 0; t < 4; ++t){
        const int r = rq*4 + t;
        float v  = acc[mt][0][r] + acc[mt][1][r];
        float v2 = acc[mt][0][r]*acc[mt][0][r] + acc[mt][1][r]*acc[mt][1][r];
        #pragma unroll
        for (int o = 1; o < 32; o <<= 1){ v += __shfl_xor(v, o, 64); v2 += __shfl_xor(v2, o, 64); }
        if (ln == 0){
          const int oc = mt*32 + 8*rq + 4*half + t;
          sc[(wid*CH + oc)*2] = v; sc[(wid*CH + oc)*2 + 1] = v2;
        }
      }
  __syncthreads();
  if (tid < CH){
    float sm = 0.f, ss = 0.f;
    #pragma unroll
    for (int w = 0; w < 4; ++w){ sm += sc[(w*CH + tid)*2]; ss += sc[(w*CH + tid)*2 + 1]; }
    part[((size_t)tid * NBLK + blockIdx.x) * 2]     = sm;
    part[((size_t)tid * NBLK + blockIdx.x) * 2 + 1] = ss;
  }
}

static void launch_conv(int dil, bool fuse, const ushort* src, const ushort* wgl,
                        const float* na, const float* nb,
                        ushort* dst, float* part, hipStream_t s){
  if (fuse){
    switch (dil){
      case 1:  convd_k<1,true><<<NBLK, 256, 0, s>>>(src, wgl, na, nb, dst, part); break;
      case 2:  convd_k<2,true><<<NBLK, 256, 0, s>>>(src, wgl, na, nb, dst, part); break;
      default: convd_k<4,true><<<NBLK, 256, 0, s>>>(src, wgl, na, nb, dst, part); break;
    }
  } else {
    switch (dil){
      case 1:  convd_k<1,false><<<NBLK, 256, 0, s>>>(src, wgl, na, nb, dst, part); break;
      case 2:  convd_k<2,false><<<NBLK, 256, 0, s>>>(src, wgl, na, nb, dst, part); break;
      default: convd_k<4,false><<<NBLK, 256, 0, s>>>(src, wgl, na, nb, dst, part); break;
    }
  }
}

extern "C" void kernel_launch(void* const* d_in, const int* in_sizes, int n_in,
                              void* d_out, int out_size, void* d_ws, size_t ws_size,
                              hipStream_t stream){
  const float* x1d    = (const float*)d_in[0];
  const float* x2     = (const float*)d_in[1];
  const float* W1     = (const float*)d_in[2];
  const float* g1     = (const float*)d_in[3];
  const float* b1     = (const float*)d_in[4];
  const float* W2     = (const float*)d_in[5];
  const float* res_w  = (const float*)d_in[11];
  const float* res_g  = (const float*)d_in[13];
  const float* res_be = (const float*)d_in[14];
  float* X = (float*)d_out;                        // fp32 NCHW residual stream

  unsigned char* wp = (unsigned char*)d_ws;
  ushort* A   = (ushort*)wp; wp += (size_t)N2 * 64 * 2;
  ushort* Bb  = (ushort*)wp; wp += (size_t)N2 * 64 * 2;
  ushort* Xb  = (ushort*)wp; wp += (size_t)N2 * 64 * 2;
  ushort* x2b = (ushort*)wp; wp += (size_t)KG2 * N2 * 16 * 2;
  ushort* wt  = (ushort*)wp; wp += (size_t)368640 * 2;
  ushort* w3b = (ushort*)wp; wp += (size_t)8192 * 2;
  ushort* w2b = (ushort*)wp; wp += (size_t)14336 * 2;
  float* fw = (float*)wp;
  float* rcP  = fw; fw += 4 * 2 * CH * SL;
  float* rowT = fw; fw += SL * CH;
  float* colT = fw; fw += SL * CH;
  float* s1m  = fw; fw += D1;   float* s1r = fw; fw += D1;
  float* s2m  = fw; fw += 256;  float* s2r = fw; fw += 256;
  float* m1   = fw; fw += 64;   float* rs1 = fw; fw += 64;
  float* aA   = fw; fw += 64;   float* bA  = fw; fw += 64;
  float* aB   = fw; fw += 64;   float* bB  = fw; fw += 64;
  float* part = fw; fw += (size_t)D2 * NBLK * 2;   // covers both stats shapes

  // ---- 1d branch
  stats_k<<<dim3(1, D1), 256, 0, stream>>>(x1d, SL, part);
  stats_final_k<<<13, 1024, 0, stream>>>(part, D1, 1, 1.f / SL, s1m, s1r);
  rowcol_k<<<dim3(2 * CH * SL / 256, 4), 256, 0, stream>>>(x1d, W1, s1r, rcP);
  rowcol_stats_k<<<CH, 256, 0, stream>>>(rcP, m1, rs1);
  rowcolT_k<<<SL * CH / 256, 256, 0, stream>>>(rcP, m1, rs1, g1, b1, rowT, colT);
  pair1n_k<<<N2 * 64 / 4096, 256, 0, stream>>>(rowT, colT, A);

  // ---- 2d branch: fused convert+stats -> MFMA GEMM
  x2cvt_k<<<dim3(XCHUNK, KG2), 256, 0, stream>>>(x2, x2b, part);
  stats_final_k<<<4, 1024, 0, stream>>>(part, D2, XCHUNK, 1.f / N2, s2m, s2r);
  w2b_k<<<56, 256, 0, stream>>>(W2, s2r, w2b);
  pair2m_k<<<NBLK, 256, 0, stream>>>(x2b, w2b, Bb, part);
  statsaffine_k<<<1, 1024, 0, stream>>>(part, NBLK, 1.f / N2,
      (const float*)d_in[6], (const float*)d_in[7], 0, aA, bA);
  norm_nhwc_k<<<N2 * 64 / 4096, 256, 0, stream>>>(Bb, aA, bA);

  // ---- mix (MFMA, in-place over A) + bootstrap X
  w3b_k<<<32, 256, 0, stream>>>((const float*)d_in[8], w3b);
  mixm_k<<<NBLK, 256, 0, stream>>>(A, Bb, w3b, A, part);
  statsaffine_k<<<1, 1024, 0, stream>>>(part, NBLK, 1.f / N2,
      (const float*)d_in[9], (const float*)d_in[10], 0, aA, bA);
  norm_res_k<<<N2 / 64, 256, 0, stream>>>(A, aA, bA, X, Xb, 0);

  // ---- conv weights
  wt_k<<<368640 / 256, 256, 0, stream>>>(res_w, wt);

  // ---- 5 residual layers x 2 convs (norm between convs fused into conv2 staging)
  const int dil[5] = {1, 2, 4, 2, 1};
  for (int layer = 0; layer < 5; ++layer){
    const int d = dil[layer];
    const int li0 = layer * 2, li1 = li0 + 1;
    launch_conv(d, false, Xb, wt + (size_t)li0 * 36864, nullptr, nullptr, A, part, stream);
    statsaffine_k<<<1, 1024, 0, stream>>>(part, NBLK, 1.f / N2, res_g, res_be, li0 * CH, aA, bA);
    launch_conv(d, true, A, wt + (size_t)li1 * 36864, aA, bA, Bb, part, stream);
    statsaffine_k<<<1, 1024, 0, stream>>>(part, NBLK, 1.f / N2, res_g, res_be, li1 * CH, aB, bB);
    norm_res_k<<<N2 / 64, 256, 0, stream>>>(Bb, aB, bB, X,
        (layer == 4) ? nullptr : Xb, 1);
  }
}